// Round 1
// baseline (8730.676 us; speedup 1.0000x reference)
//
#include <hip/hip_runtime.h>
#include <cstdint>
#include <cstddef>

// ---------------------------------------------------------------------------
// Sizes (fixed by the problem)
// ---------------------------------------------------------------------------
constexpr int Tn = 12, Bn = 16, Nn = 1024, Hn = 64, Ln = 2, PROJn = 256;
constexpr int ROWS = Bn * Nn;              // 16384 rows per dir (b,n)
constexpr int TOT  = Tn * Bn * Nn;         // 196608 (t,b,n) rows
constexpr int HALF = TOT / 2;              // 98304 threefry calls
constexpr size_t HSZ = (size_t)Bn * Nn * Hn;  // 1048576 floats per [b,n,64] plane

#define DEVFN __device__ __forceinline__

// ---------------------------------------------------------------------------
// JAX threefry2x32 (key = (0,42)) + uniform->normal conversion (XLA-exact)
// ---------------------------------------------------------------------------
DEVFN uint32_t rotl32(uint32_t v, int d) { return (v << d) | (v >> (32 - d)); }

DEVFN void threefry_0_42(uint32_t& x0, uint32_t& x1) {
  const uint32_t k0 = 0u, k1 = 42u, k2 = k0 ^ k1 ^ 0x1BD11BDAu;
  x0 += k0; x1 += k1;
#define TFR(r) { x0 += x1; x1 = rotl32(x1, r); x1 ^= x0; }
  TFR(13) TFR(15) TFR(26) TFR(6)
  x0 += k1; x1 += k2 + 1u;
  TFR(17) TFR(29) TFR(16) TFR(24)
  x0 += k2; x1 += k0 + 2u;
  TFR(13) TFR(15) TFR(26) TFR(6)
  x0 += k0; x1 += k1 + 3u;
  TFR(17) TFR(29) TFR(16) TFR(24)
  x0 += k1; x1 += k2 + 4u;
  TFR(13) TFR(15) TFR(26) TFR(6)
  x0 += k2; x1 += k0 + 5u;
#undef TFR
}

// Giles erfinv (the polynomial XLA lowers lax.erf_inv to for f32)
DEVFN float erfinv32(float x) {
  float w = -log1pf(-x * x);
  float p;
  if (w < 5.0f) {
    w = w - 2.5f;
    p = 2.81022636e-08f;
    p = fmaf(p, w, 3.43273939e-07f);
    p = fmaf(p, w, -3.5233877e-06f);
    p = fmaf(p, w, -4.39150654e-06f);
    p = fmaf(p, w, 0.00021858087f);
    p = fmaf(p, w, -0.00125372503f);
    p = fmaf(p, w, -0.00417768164f);
    p = fmaf(p, w, 0.246640727f);
    p = fmaf(p, w, 1.50140941f);
  } else {
    w = sqrtf(w) - 3.0f;
    p = -0.000200214257f;
    p = fmaf(p, w, 0.000100950558f);
    p = fmaf(p, w, 0.00134934322f);
    p = fmaf(p, w, -0.00367342844f);
    p = fmaf(p, w, 0.00573950773f);
    p = fmaf(p, w, -0.0076224613f);
    p = fmaf(p, w, 0.00943887047f);
    p = fmaf(p, w, 1.00167406f);
    p = fmaf(p, w, 2.83297682f);
  }
  return p * x;
}

DEVFN float bits_to_normal(uint32_t bits) {
  // uniform in [1,2) - 1 -> [0,1); affine to [lo, 1); clamp; sqrt(2)*erfinv
  float f = __uint_as_float((bits >> 9) | 0x3f800000u) - 1.0f;
  const float lo = -0.99999994f;          // nextafter(-1,0)
  float u = fmaf(f, 2.0f, lo);            // (1 - lo) rounds to 2.0f in fp32
  u = fmaxf(lo, u);
  return 1.41421356237f * erfinv32(u);
}

__global__ __launch_bounds__(256) void seq_kernel(const float* __restrict__ inputs,
                                                  float* __restrict__ s0) {
  int i = blockIdx.x * 256 + threadIdx.x;
  if (i >= HALF) return;
  uint32_t x0 = (uint32_t)i, x1 = (uint32_t)(i + HALF);
  threefry_0_42(x0, x1);
  s0[i]        = inputs[i]        + 0.01f * bits_to_normal(x0);
  s0[i + HALF] = inputs[i + HALF] + 0.01f * bits_to_normal(x1);
}

DEVFN float sigmoidf_(float x) { return 1.0f / (1.0f + expf(-x)); }

// ---------------------------------------------------------------------------
// Graph conv: agg[dir][b*1024+n][f] = sum_m adj[n][m] * ([x|h])[b][m][f]
// Tile 128(n) x 128(f), BK=8, 256 thr, 8x8 per thread.
// ---------------------------------------------------------------------------
__global__ __launch_bounds__(256) void conv_kernel(
    const float* __restrict__ adj,
    const float* __restrict__ x0p, const float* __restrict__ x1p,
    const float* __restrict__ h0p, const float* __restrict__ h1p,
    float* __restrict__ agg)
{
  __shared__ __align__(16) float As[8][132];
  __shared__ __align__(16) float Bs[8][132];
  const int tid = threadIdx.x;
  const int n0  = blockIdx.x * 128;
  const int b   = blockIdx.y;
  const int dir = blockIdx.z;
  const float* __restrict__ xs = dir ? x1p : x0p;
  const float* __restrict__ hs = dir ? h1p : h0p;
  float* __restrict__ aggd = agg + (size_t)dir * ((size_t)ROWS * 128) + (size_t)b * (Nn * 128);

  const int a_nl = tid >> 1, a_k0 = (tid & 1) * 4;
  const int b_kk = tid >> 5, b_f0 = (tid & 31) * 4;
  const int tx = tid & 15, ty = tid >> 4;

  float acc[8][8];
#pragma unroll
  for (int i = 0; i < 8; ++i)
#pragma unroll
    for (int j = 0; j < 8; ++j) acc[i][j] = 0.0f;

  const float* aptr = adj + (size_t)(n0 + a_nl) * Nn + a_k0;
  const float* bbase = (b_f0 < 64)
      ? (xs + (size_t)(b * Nn + b_kk) * 64 + b_f0)
      : (hs + (size_t)(b * Nn + b_kk) * 64 + (b_f0 - 64));

  for (int kt = 0; kt < Nn; kt += 8) {
    float4 av = *reinterpret_cast<const float4*>(aptr + kt);
    float4 bv = *reinterpret_cast<const float4*>(bbase + (size_t)kt * 64);
    __syncthreads();
    As[a_k0 + 0][a_nl] = av.x;
    As[a_k0 + 1][a_nl] = av.y;
    As[a_k0 + 2][a_nl] = av.z;
    As[a_k0 + 3][a_nl] = av.w;
    *reinterpret_cast<float4*>(&Bs[b_kk][b_f0]) = bv;
    __syncthreads();
#pragma unroll
    for (int kk = 0; kk < 8; ++kk) {
      const float4 a0 = *reinterpret_cast<const float4*>(&As[kk][ty * 8]);
      const float4 a1 = *reinterpret_cast<const float4*>(&As[kk][ty * 8 + 4]);
      const float4 b0 = *reinterpret_cast<const float4*>(&Bs[kk][tx * 8]);
      const float4 b1 = *reinterpret_cast<const float4*>(&Bs[kk][tx * 8 + 4]);
      const float avv[8] = {a0.x, a0.y, a0.z, a0.w, a1.x, a1.y, a1.z, a1.w};
      const float bvv[8] = {b0.x, b0.y, b0.z, b0.w, b1.x, b1.y, b1.z, b1.w};
#pragma unroll
      for (int i = 0; i < 8; ++i)
#pragma unroll
        for (int j = 0; j < 8; ++j)
          acc[i][j] = fmaf(avv[i], bvv[j], acc[i][j]);
    }
  }
#pragma unroll
  for (int i = 0; i < 8; ++i) {
    const int n = n0 + ty * 8 + i;
    float* cp = aggd + (size_t)n * 128 + tx * 8;
    *reinterpret_cast<float4*>(cp)     = make_float4(acc[i][0], acc[i][1], acc[i][2], acc[i][3]);
    *reinterpret_cast<float4*>(cp + 4) = make_float4(acc[i][4], acc[i][5], acc[i][6], acc[i][7]);
  }
}

// ---------------------------------------------------------------------------
// z/r gates: [16384,128] @ [Wz|Wr] -> z = sig(+bz), rh = sig(+br)*h
// ---------------------------------------------------------------------------
__global__ __launch_bounds__(256) void zr_kernel(
    const float* __restrict__ agg,
    const float* __restrict__ WzF, const float* __restrict__ WzR,
    const float* __restrict__ WrF, const float* __restrict__ WrR,
    const float* __restrict__ bzF, const float* __restrict__ bzR,
    const float* __restrict__ brF, const float* __restrict__ brR,
    const float* __restrict__ h0p, const float* __restrict__ h1p,
    float* __restrict__ zbuf, float* __restrict__ rhbuf)
{
  __shared__ __align__(16) float As[8][132];
  __shared__ __align__(16) float Bs[8][132];
  const int tid = threadIdx.x;
  const int row0 = blockIdx.x * 128;
  const int dir  = blockIdx.z;
  const float* __restrict__ Wz = dir ? WzR : WzF;
  const float* __restrict__ Wr = dir ? WrR : WrF;
  const float* __restrict__ bz = dir ? bzR : bzF;
  const float* __restrict__ br = dir ? brR : brF;
  const float* __restrict__ hb = dir ? h1p : h0p;
  const float* aggd = agg + (size_t)dir * ((size_t)ROWS * 128);
  float* zb = zbuf  + (size_t)dir * ((size_t)ROWS * 64);
  float* rb = rhbuf + (size_t)dir * ((size_t)ROWS * 64);

  const int a_nl = tid >> 1, a_k0 = (tid & 1) * 4;
  const int b_kk = tid >> 5, b_f0 = (tid & 31) * 4;
  const int tx = tid & 15, ty = tid >> 4;

  float acc[8][8];
#pragma unroll
  for (int i = 0; i < 8; ++i)
#pragma unroll
    for (int j = 0; j < 8; ++j) acc[i][j] = 0.0f;

  const float* aptr = aggd + (size_t)(row0 + a_nl) * 128 + a_k0;
  const float* wsrc = (b_f0 < 64) ? (Wz + b_f0) : (Wr + (b_f0 - 64));

  for (int kt = 0; kt < 128; kt += 8) {
    float4 av = *reinterpret_cast<const float4*>(aptr + kt);
    float4 bv = *reinterpret_cast<const float4*>(wsrc + (size_t)(kt + b_kk) * 64);
    __syncthreads();
    As[a_k0 + 0][a_nl] = av.x;
    As[a_k0 + 1][a_nl] = av.y;
    As[a_k0 + 2][a_nl] = av.z;
    As[a_k0 + 3][a_nl] = av.w;
    *reinterpret_cast<float4*>(&Bs[b_kk][b_f0]) = bv;
    __syncthreads();
#pragma unroll
    for (int kk = 0; kk < 8; ++kk) {
      const float4 a0 = *reinterpret_cast<const float4*>(&As[kk][ty * 8]);
      const float4 a1 = *reinterpret_cast<const float4*>(&As[kk][ty * 8 + 4]);
      const float4 b0 = *reinterpret_cast<const float4*>(&Bs[kk][tx * 8]);
      const float4 b1 = *reinterpret_cast<const float4*>(&Bs[kk][tx * 8 + 4]);
      const float avv[8] = {a0.x, a0.y, a0.z, a0.w, a1.x, a1.y, a1.z, a1.w};
      const float bvv[8] = {b0.x, b0.y, b0.z, b0.w, b1.x, b1.y, b1.z, b1.w};
#pragma unroll
      for (int i = 0; i < 8; ++i)
#pragma unroll
        for (int j = 0; j < 8; ++j)
          acc[i][j] = fmaf(avv[i], bvv[j], acc[i][j]);
    }
  }

  if (tx < 8) {                 // z columns 0..63
    const int c0 = tx * 8;
#pragma unroll
    for (int i = 0; i < 8; ++i) {
      const int row = row0 + ty * 8 + i;
      float o[8];
#pragma unroll
      for (int j = 0; j < 8; ++j) o[j] = sigmoidf_(acc[i][j] + bz[c0 + j]);
      float* p = zb + (size_t)row * 64 + c0;
      *reinterpret_cast<float4*>(p)     = make_float4(o[0], o[1], o[2], o[3]);
      *reinterpret_cast<float4*>(p + 4) = make_float4(o[4], o[5], o[6], o[7]);
    }
  } else {                      // r columns -> rh = r*h
    const int c0 = (tx - 8) * 8;
#pragma unroll
    for (int i = 0; i < 8; ++i) {
      const int row = row0 + ty * 8 + i;
      const float* hp = hb + (size_t)row * 64 + c0;
      float o[8];
#pragma unroll
      for (int j = 0; j < 8; ++j) {
        float r = sigmoidf_(acc[i][j] + br[c0 + j]);
        o[j] = r * hp[j];
      }
      float* p = rb + (size_t)row * 64 + c0;
      *reinterpret_cast<float4*>(p)     = make_float4(o[0], o[1], o[2], o[3]);
      *reinterpret_cast<float4*>(p + 4) = make_float4(o[4], o[5], o[6], o[7]);
    }
  }
}

// ---------------------------------------------------------------------------
// c gate + GRU update: c = tanh(agg2@Wc+bc); h = z*h + (1-z)*c   (in place)
// BN=64, 8x4 per thread.
// ---------------------------------------------------------------------------
__global__ __launch_bounds__(256) void cup_kernel(
    const float* __restrict__ agg,
    const float* __restrict__ WcF, const float* __restrict__ WcR,
    const float* __restrict__ bcF, const float* __restrict__ bcR,
    const float* __restrict__ zbuf,
    float* __restrict__ h0p, float* __restrict__ h1p)
{
  __shared__ __align__(16) float As[8][132];
  __shared__ __align__(16) float Bs[8][68];
  const int tid = threadIdx.x;
  const int row0 = blockIdx.x * 128;
  const int dir  = blockIdx.z;
  const float* __restrict__ Wc = dir ? WcR : WcF;
  const float* __restrict__ bc = dir ? bcR : bcF;
  float* __restrict__ hb = dir ? h1p : h0p;
  const float* aggd = agg + (size_t)dir * ((size_t)ROWS * 128);
  const float* zb = zbuf + (size_t)dir * ((size_t)ROWS * 64);

  const int a_nl = tid >> 1, a_k0 = (tid & 1) * 4;
  const int w_kk = tid >> 4, w_c0 = (tid & 15) * 4;   // threads < 128 load B
  const int tx = tid & 15, ty = tid >> 4;

  float acc[8][4];
#pragma unroll
  for (int i = 0; i < 8; ++i)
#pragma unroll
    for (int j = 0; j < 4; ++j) acc[i][j] = 0.0f;

  const float* aptr = aggd + (size_t)(row0 + a_nl) * 128 + a_k0;

  for (int kt = 0; kt < 128; kt += 8) {
    float4 av = *reinterpret_cast<const float4*>(aptr + kt);
    float4 wv = make_float4(0.f, 0.f, 0.f, 0.f);
    if (tid < 128) wv = *reinterpret_cast<const float4*>(Wc + (size_t)(kt + w_kk) * 64 + w_c0);
    __syncthreads();
    As[a_k0 + 0][a_nl] = av.x;
    As[a_k0 + 1][a_nl] = av.y;
    As[a_k0 + 2][a_nl] = av.z;
    As[a_k0 + 3][a_nl] = av.w;
    if (tid < 128) *reinterpret_cast<float4*>(&Bs[w_kk][w_c0]) = wv;
    __syncthreads();
#pragma unroll
    for (int kk = 0; kk < 8; ++kk) {
      const float4 a0 = *reinterpret_cast<const float4*>(&As[kk][ty * 8]);
      const float4 a1 = *reinterpret_cast<const float4*>(&As[kk][ty * 8 + 4]);
      const float4 b0 = *reinterpret_cast<const float4*>(&Bs[kk][tx * 4]);
      const float avv[8] = {a0.x, a0.y, a0.z, a0.w, a1.x, a1.y, a1.z, a1.w};
      const float bvv[4] = {b0.x, b0.y, b0.z, b0.w};
#pragma unroll
      for (int i = 0; i < 8; ++i)
#pragma unroll
        for (int j = 0; j < 4; ++j)
          acc[i][j] = fmaf(avv[i], bvv[j], acc[i][j]);
    }
  }
#pragma unroll
  for (int i = 0; i < 8; ++i) {
    const int row = row0 + ty * 8 + i;
    const float4 zv = *reinterpret_cast<const float4*>(zb + (size_t)row * 64 + tx * 4);
    float* hp = hb + (size_t)row * 64 + tx * 4;
    const float4 hv = *reinterpret_cast<const float4*>(hp);
    const float zz[4] = {zv.x, zv.y, zv.z, zv.w};
    const float hh[4] = {hv.x, hv.y, hv.z, hv.w};
    float o[4];
#pragma unroll
    for (int j = 0; j < 4; ++j) {
      float c = tanhf(acc[i][j] + bc[tx * 4 + j]);
      o[j] = zz[j] * hh[j] + (1.0f - zz[j]) * c;
    }
    *reinterpret_cast<float4*>(hp) = make_float4(o[0], o[1], o[2], o[3]);
  }
}

// ---------------------------------------------------------------------------
// Projection: X[row][h] = relu(s0*Wp1[0]+s1*Wp1[1]+bp1) @ Wp2 + bp2
// A-tile generated on the fly. BN=64, K=256.
// ---------------------------------------------------------------------------
__global__ __launch_bounds__(256) void proj_kernel(
    const float* __restrict__ s0g, const float* __restrict__ s1g,
    const float* __restrict__ Wp1, const float* __restrict__ bp1,
    const float* __restrict__ Wp2, const float* __restrict__ bp2,
    float* __restrict__ X)
{
  __shared__ __align__(16) float As[8][132];
  __shared__ __align__(16) float Bs[8][68];
  __shared__ float W0[256], W1[256], Wb[256], Ss0[128], Ss1[128];
  const int tid = threadIdx.x;
  const int row0 = blockIdx.x * 128;
  W0[tid] = Wp1[tid];
  W1[tid] = Wp1[256 + tid];
  Wb[tid] = bp1[tid];
  if (tid < 128) { Ss0[tid] = s0g[row0 + tid]; Ss1[tid] = s1g[row0 + tid]; }
  __syncthreads();

  const int a_nl = tid >> 1, a_kb = (tid & 1) * 4;
  const int w_kk = tid >> 4, w_c0 = (tid & 15) * 4;
  const int tx = tid & 15, ty = tid >> 4;
  const float sv0 = Ss0[a_nl], sv1 = Ss1[a_nl];

  float acc[8][4];
#pragma unroll
  for (int i = 0; i < 8; ++i)
#pragma unroll
    for (int j = 0; j < 4; ++j) acc[i][j] = 0.0f;

  for (int kt = 0; kt < 256; kt += 8) {
    float4 wv = make_float4(0.f, 0.f, 0.f, 0.f);
    if (tid < 128) wv = *reinterpret_cast<const float4*>(Wp2 + (size_t)(kt + w_kk) * 64 + w_c0);
    __syncthreads();
#pragma unroll
    for (int u = 0; u < 4; ++u) {
      const int p = kt + a_kb + u;
      float v = fmaf(sv0, W0[p], fmaf(sv1, W1[p], Wb[p]));
      As[a_kb + u][a_nl] = fmaxf(v, 0.0f);
    }
    if (tid < 128) *reinterpret_cast<float4*>(&Bs[w_kk][w_c0]) = wv;
    __syncthreads();
#pragma unroll
    for (int kk = 0; kk < 8; ++kk) {
      const float4 a0 = *reinterpret_cast<const float4*>(&As[kk][ty * 8]);
      const float4 a1 = *reinterpret_cast<const float4*>(&As[kk][ty * 8 + 4]);
      const float4 b0 = *reinterpret_cast<const float4*>(&Bs[kk][tx * 4]);
      const float avv[8] = {a0.x, a0.y, a0.z, a0.w, a1.x, a1.y, a1.z, a1.w};
      const float bvv[4] = {b0.x, b0.y, b0.z, b0.w};
#pragma unroll
      for (int i = 0; i < 8; ++i)
#pragma unroll
        for (int j = 0; j < 4; ++j)
          acc[i][j] = fmaf(avv[i], bvv[j], acc[i][j]);
    }
  }
#pragma unroll
  for (int i = 0; i < 8; ++i) {
    const int row = row0 + ty * 8 + i;
    float o[4];
#pragma unroll
    for (int j = 0; j < 4; ++j) o[j] = acc[i][j] + bp2[tx * 4 + j];
    *reinterpret_cast<float4*>(X + (size_t)row * 64 + tx * 4) = make_float4(o[0], o[1], o[2], o[3]);
  }
}

// ---------------------------------------------------------------------------
// Decoder stage 1: D1[row][c] = relu(concat(hid_f,hid_r)[row] @ Wd1 + bd1)
// rows = l*16384 + (b*1024+n); BN=128, K=128.
// ---------------------------------------------------------------------------
__global__ __launch_bounds__(256) void dec1_kernel(
    const float* __restrict__ Hws,     // [dir*2+l][16384][64]
    const float* __restrict__ Wd1, const float* __restrict__ bd1,
    float* __restrict__ D1)
{
  __shared__ __align__(16) float As[8][132];
  __shared__ __align__(16) float Bs[8][132];
  const int tid = threadIdx.x;
  const int row0 = blockIdx.x * 128;
  const int cb   = blockIdx.y * 128;
  const int a_nl = tid >> 1, a_k0 = (tid & 1) * 4;
  const int b_kk = tid >> 5, b_f0 = (tid & 31) * 4;
  const int tx = tid & 15, ty = tid >> 4;

  float acc[8][8];
#pragma unroll
  for (int i = 0; i < 8; ++i)
#pragma unroll
    for (int j = 0; j < 8; ++j) acc[i][j] = 0.0f;

  const int arow = row0 + a_nl;
  const int l  = arow >> 14;            // row / 16384
  const int ri = arow & 16383;

  for (int kt = 0; kt < 128; kt += 8) {
    const int k0 = kt + a_k0;
    const float* abase = (k0 < 64)
        ? (Hws + (size_t)l * HSZ + (size_t)ri * 64 + k0)            // hid_f[l]
        : (Hws + (size_t)(2 + l) * HSZ + (size_t)ri * 64 + (k0 - 64)); // hid_r[l]
    float4 av = *reinterpret_cast<const float4*>(abase);
    float4 bv = *reinterpret_cast<const float4*>(Wd1 + (size_t)(kt + b_kk) * 256 + cb + b_f0);
    __syncthreads();
    As[a_k0 + 0][a_nl] = av.x;
    As[a_k0 + 1][a_nl] = av.y;
    As[a_k0 + 2][a_nl] = av.z;
    As[a_k0 + 3][a_nl] = av.w;
    *reinterpret_cast<float4*>(&Bs[b_kk][b_f0]) = bv;
    __syncthreads();
#pragma unroll
    for (int kk = 0; kk < 8; ++kk) {
      const float4 a0 = *reinterpret_cast<const float4*>(&As[kk][ty * 8]);
      const float4 a1 = *reinterpret_cast<const float4*>(&As[kk][ty * 8 + 4]);
      const float4 b0 = *reinterpret_cast<const float4*>(&Bs[kk][tx * 8]);
      const float4 b1 = *reinterpret_cast<const float4*>(&Bs[kk][tx * 8 + 4]);
      const float avv[8] = {a0.x, a0.y, a0.z, a0.w, a1.x, a1.y, a1.z, a1.w};
      const float bvv[8] = {b0.x, b0.y, b0.z, b0.w, b1.x, b1.y, b1.z, b1.w};
#pragma unroll
      for (int i = 0; i < 8; ++i)
#pragma unroll
        for (int j = 0; j < 8; ++j)
          acc[i][j] = fmaf(avv[i], bvv[j], acc[i][j]);
    }
  }
#pragma unroll
  for (int i = 0; i < 8; ++i) {
    const int row = row0 + ty * 8 + i;
    float* p = D1 + (size_t)row * 256 + cb + tx * 8;
    float o[8];
#pragma unroll
    for (int j = 0; j < 8; ++j) o[j] = fmaxf(acc[i][j] + bd1[cb + tx * 8 + j], 0.0f);
    *reinterpret_cast<float4*>(p)     = make_float4(o[0], o[1], o[2], o[3]);
    *reinterpret_cast<float4*>(p + 4) = make_float4(o[4], o[5], o[6], o[7]);
  }
}

// ---------------------------------------------------------------------------
// Decoder stage 2: out[row][h] = D1[row] @ Wd2 + bd2   (BN=64, K=256)
// ---------------------------------------------------------------------------
__global__ __launch_bounds__(256) void dec2_kernel(
    const float* __restrict__ D1, const float* __restrict__ Wd2,
    const float* __restrict__ bd2, float* __restrict__ out)
{
  __shared__ __align__(16) float As[8][132];
  __shared__ __align__(16) float Bs[8][68];
  const int tid = threadIdx.x;
  const int row0 = blockIdx.x * 128;
  const int a_nl = tid >> 1, a_k0 = (tid & 1) * 4;
  const int w_kk = tid >> 4, w_c0 = (tid & 15) * 4;
  const int tx = tid & 15, ty = tid >> 4;

  float acc[8][4];
#pragma unroll
  for (int i = 0; i < 8; ++i)
#pragma unroll
    for (int j = 0; j < 4; ++j) acc[i][j] = 0.0f;

  const float* aptr = D1 + (size_t)(row0 + a_nl) * 256 + a_k0;

  for (int kt = 0; kt < 256; kt += 8) {
    float4 av = *reinterpret_cast<const float4*>(aptr + kt);
    float4 wv = make_float4(0.f, 0.f, 0.f, 0.f);
    if (tid < 128) wv = *reinterpret_cast<const float4*>(Wd2 + (size_t)(kt + w_kk) * 64 + w_c0);
    __syncthreads();
    As[a_k0 + 0][a_nl] = av.x;
    As[a_k0 + 1][a_nl] = av.y;
    As[a_k0 + 2][a_nl] = av.z;
    As[a_k0 + 3][a_nl] = av.w;
    if (tid < 128) *reinterpret_cast<float4*>(&Bs[w_kk][w_c0]) = wv;
    __syncthreads();
#pragma unroll
    for (int kk = 0; kk < 8; ++kk) {
      const float4 a0 = *reinterpret_cast<const float4*>(&As[kk][ty * 8]);
      const float4 a1 = *reinterpret_cast<const float4*>(&As[kk][ty * 8 + 4]);
      const float4 b0 = *reinterpret_cast<const float4*>(&Bs[kk][tx * 4]);
      const float avv[8] = {a0.x, a0.y, a0.z, a0.w, a1.x, a1.y, a1.z, a1.w};
      const float bvv[4] = {b0.x, b0.y, b0.z, b0.w};
#pragma unroll
      for (int i = 0; i < 8; ++i)
#pragma unroll
        for (int j = 0; j < 4; ++j)
          acc[i][j] = fmaf(avv[i], bvv[j], acc[i][j]);
    }
  }
#pragma unroll
  for (int i = 0; i < 8; ++i) {
    const int row = row0 + ty * 8 + i;
    float o[4];
#pragma unroll
    for (int j = 0; j < 4; ++j) o[j] = acc[i][j] + bd2[tx * 4 + j];
    *reinterpret_cast<float4*>(out + (size_t)row * 64 + tx * 4) = make_float4(o[0], o[1], o[2], o[3]);
  }
}

// ---------------------------------------------------------------------------
// Host driver
// ---------------------------------------------------------------------------
extern "C" void kernel_launch(void* const* d_in, const int* in_sizes, int n_in,
                              void* d_out, int out_size, void* d_ws, size_t ws_size,
                              hipStream_t stream)
{
  (void)in_sizes; (void)n_in; (void)out_size; (void)ws_size;
  const float* inputs = (const float*)d_in[0];
  const float* mask   = (const float*)d_in[1];
  const float* adj    = (const float*)d_in[2];
  const float* Wp1    = (const float*)d_in[3];
  const float* bp1    = (const float*)d_in[4];
  const float* Wp2    = (const float*)d_in[5];
  const float* bp2    = (const float*)d_in[6];
  const float* Wz_f   = (const float*)d_in[7];
  const float* Wr_f   = (const float*)d_in[8];
  const float* Wc_f   = (const float*)d_in[9];
  const float* bz_f   = (const float*)d_in[10];
  const float* br_f   = (const float*)d_in[11];
  const float* bc_f   = (const float*)d_in[12];
  const float* Wz_r   = (const float*)d_in[13];
  const float* Wr_r   = (const float*)d_in[14];
  const float* Wc_r   = (const float*)d_in[15];
  const float* bz_r   = (const float*)d_in[16];
  const float* br_r   = (const float*)d_in[17];
  const float* bc_r   = (const float*)d_in[18];
  const float* Wd1    = (const float*)d_in[19];
  const float* bd1    = (const float*)d_in[20];
  const float* Wd2    = (const float*)d_in[21];
  const float* bd2    = (const float*)d_in[22];

  float* ws = (float*)d_ws;
  float* S0 = ws;                                   // 196608
  float* X  = S0 + TOT;                             // 196608*64
  float* H  = X + (size_t)TOT * 64;                 // 4 * HSZ   [dir*2+l]
  float* AG = H + 4 * HSZ;                          // 2 * 16384*128
  float* Z  = AG + 2 * (size_t)ROWS * 128;          // 2 * HSZ
  float* RH = Z + 2 * HSZ;                          // 2 * HSZ
  float* D1 = RH + 2 * HSZ;                         // 32768*256

  hipMemsetAsync(H, 0, 4 * HSZ * sizeof(float), stream);

  seq_kernel<<<dim3((HALF + 255) / 256), 256, 0, stream>>>(inputs, S0);
  proj_kernel<<<dim3(TOT / 128), 256, 0, stream>>>(S0, mask, Wp1, bp1, Wp2, bp2, X);

  for (int t = 0; t < Tn; ++t) {
    for (int l = 0; l < Ln; ++l) {
      const float* x0 = (l == 0) ? (X + (size_t)t * HSZ) : H;                 // dir0 input
      const float* x1 = (l == 0) ? (X + (size_t)(Tn - 1 - t) * HSZ) : (H + 2 * HSZ); // dir1 input
      float* h0 = H + (size_t)l * HSZ;
      float* h1 = H + (size_t)(2 + l) * HSZ;
      // agg = adj @ [x | h]
      conv_kernel<<<dim3(8, 16, 2), 256, 0, stream>>>(adj, x0, x1, h0, h1, AG);
      // z, rh = sigmoid gates
      zr_kernel<<<dim3(128, 1, 2), 256, 0, stream>>>(AG,
          Wz_f + l * 8192, Wz_r + l * 8192, Wr_f + l * 8192, Wr_r + l * 8192,
          bz_f + l * 64, bz_r + l * 64, br_f + l * 64, br_r + l * 64,
          h0, h1, Z, RH);
      // agg2 = adj @ [x | r*h]
      conv_kernel<<<dim3(8, 16, 2), 256, 0, stream>>>(adj, x0, x1, RH, RH + HSZ, AG);
      // c = tanh(...); h = z*h + (1-z)*c
      cup_kernel<<<dim3(128, 1, 2), 256, 0, stream>>>(AG,
          Wc_f + l * 8192, Wc_r + l * 8192, bc_f + l * 64, bc_r + l * 64,
          Z, h0, h1);
    }
  }

  dec1_kernel<<<dim3(256, 2), 256, 0, stream>>>(H, Wd1, bd1, D1);
  dec2_kernel<<<dim3(256, 1), 256, 0, stream>>>(D1, Wd2, bd2, (float*)d_out);
}

// Round 2
// 5866.407 us; speedup vs baseline: 1.4882x; 1.4882x over previous
//
#include <hip/hip_runtime.h>
#include <cstdint>
#include <cstddef>

constexpr int Tn = 12, Bn = 16, Nn = 1024, Hn = 64, Ln = 2, PROJn = 256;
constexpr int ROWS = Bn * Nn;                 // 16384
constexpr int TOT  = Tn * Bn * Nn;            // 196608
constexpr int HALF = TOT / 2;
constexpr size_t HSZ = (size_t)Bn * Nn * Hn;  // 1048576 floats

#define DEVFN __device__ __forceinline__

// ---------------------------------------------------------------------------
// threefry2x32 (key 0,42) + XLA-exact normal
// ---------------------------------------------------------------------------
DEVFN uint32_t rotl32(uint32_t v, int d) { return (v << d) | (v >> (32 - d)); }

DEVFN void threefry_0_42(uint32_t& x0, uint32_t& x1) {
  const uint32_t k0 = 0u, k1 = 42u, k2 = k0 ^ k1 ^ 0x1BD11BDAu;
  x0 += k0; x1 += k1;
#define TFR(r) { x0 += x1; x1 = rotl32(x1, r); x1 ^= x0; }
  TFR(13) TFR(15) TFR(26) TFR(6)
  x0 += k1; x1 += k2 + 1u;
  TFR(17) TFR(29) TFR(16) TFR(24)
  x0 += k2; x1 += k0 + 2u;
  TFR(13) TFR(15) TFR(26) TFR(6)
  x0 += k0; x1 += k1 + 3u;
  TFR(17) TFR(29) TFR(16) TFR(24)
  x0 += k1; x1 += k2 + 4u;
  TFR(13) TFR(15) TFR(26) TFR(6)
  x0 += k2; x1 += k0 + 5u;
#undef TFR
}

DEVFN float erfinv32(float x) {
  float w = -log1pf(-x * x);
  float p;
  if (w < 5.0f) {
    w = w - 2.5f;
    p = 2.81022636e-08f;
    p = fmaf(p, w, 3.43273939e-07f);
    p = fmaf(p, w, -3.5233877e-06f);
    p = fmaf(p, w, -4.39150654e-06f);
    p = fmaf(p, w, 0.00021858087f);
    p = fmaf(p, w, -0.00125372503f);
    p = fmaf(p, w, -0.00417768164f);
    p = fmaf(p, w, 0.246640727f);
    p = fmaf(p, w, 1.50140941f);
  } else {
    w = sqrtf(w) - 3.0f;
    p = -0.000200214257f;
    p = fmaf(p, w, 0.000100950558f);
    p = fmaf(p, w, 0.00134934322f);
    p = fmaf(p, w, -0.00367342844f);
    p = fmaf(p, w, 0.00573950773f);
    p = fmaf(p, w, -0.0076224613f);
    p = fmaf(p, w, 0.00943887047f);
    p = fmaf(p, w, 1.00167406f);
    p = fmaf(p, w, 2.83297682f);
  }
  return p * x;
}

DEVFN float bits_to_normal(uint32_t bits) {
  float f = __uint_as_float((bits >> 9) | 0x3f800000u) - 1.0f;
  const float lo = -0.99999994f;
  float u = fmaf(f, 2.0f, lo);
  u = fmaxf(lo, u);
  return 1.41421356237f * erfinv32(u);
}

__global__ __launch_bounds__(256) void seq_kernel(const float* __restrict__ inputs,
                                                  float* __restrict__ s0) {
  int i = blockIdx.x * 256 + threadIdx.x;
  if (i >= HALF) return;
  uint32_t x0 = (uint32_t)i, x1 = (uint32_t)(i + HALF);
  threefry_0_42(x0, x1);
  s0[i]        = inputs[i]        + 0.01f * bits_to_normal(x0);
  s0[i + HALF] = inputs[i + HALF] + 0.01f * bits_to_normal(x1);
}

DEVFN float sigmoidf_(float x) { return 1.0f / (1.0f + expf(-x)); }

// ---------------------------------------------------------------------------
// Projection: X[row][h] = relu(s0*Wp1[0]+s1*Wp1[1]+bp1) @ Wp2 + bp2
// ---------------------------------------------------------------------------
__global__ __launch_bounds__(256) void proj_kernel(
    const float* __restrict__ s0g, const float* __restrict__ s1g,
    const float* __restrict__ Wp1, const float* __restrict__ bp1,
    const float* __restrict__ Wp2, const float* __restrict__ bp2,
    float* __restrict__ X)
{
  __shared__ __align__(16) float As[8][132];
  __shared__ __align__(16) float Bs[8][68];
  __shared__ float W0[256], W1[256], Wb[256], Ss0[128], Ss1[128];
  const int tid = threadIdx.x;
  const int row0 = blockIdx.x * 128;
  W0[tid] = Wp1[tid];
  W1[tid] = Wp1[256 + tid];
  Wb[tid] = bp1[tid];
  if (tid < 128) { Ss0[tid] = s0g[row0 + tid]; Ss1[tid] = s1g[row0 + tid]; }
  __syncthreads();

  const int a_nl = tid >> 1, a_kb = (tid & 1) * 4;
  const int w_kk = tid >> 4, w_c0 = (tid & 15) * 4;
  const int tx = tid & 15, ty = tid >> 4;
  const float sv0 = Ss0[a_nl], sv1 = Ss1[a_nl];

  float acc[8][4] = {};
  for (int kt = 0; kt < 256; kt += 8) {
    float4 wv = make_float4(0.f, 0.f, 0.f, 0.f);
    if (tid < 128) wv = *reinterpret_cast<const float4*>(Wp2 + (size_t)(kt + w_kk) * 64 + w_c0);
    __syncthreads();
#pragma unroll
    for (int u = 0; u < 4; ++u) {
      const int p = kt + a_kb + u;
      float v = fmaf(sv0, W0[p], fmaf(sv1, W1[p], Wb[p]));
      As[a_kb + u][a_nl] = fmaxf(v, 0.0f);
    }
    if (tid < 128) *reinterpret_cast<float4*>(&Bs[w_kk][w_c0]) = wv;
    __syncthreads();
#pragma unroll
    for (int kk = 0; kk < 8; ++kk) {
      const float4 a0 = *reinterpret_cast<const float4*>(&As[kk][ty * 8]);
      const float4 a1 = *reinterpret_cast<const float4*>(&As[kk][ty * 8 + 4]);
      const float4 b0 = *reinterpret_cast<const float4*>(&Bs[kk][tx * 4]);
      const float avv[8] = {a0.x, a0.y, a0.z, a0.w, a1.x, a1.y, a1.z, a1.w};
      const float bvv[4] = {b0.x, b0.y, b0.z, b0.w};
#pragma unroll
      for (int i = 0; i < 8; ++i)
#pragma unroll
        for (int j = 0; j < 4; ++j)
          acc[i][j] = fmaf(avv[i], bvv[j], acc[i][j]);
    }
  }
#pragma unroll
  for (int i = 0; i < 8; ++i) {
    const int row = row0 + ty * 8 + i;
    float o[4];
#pragma unroll
    for (int j = 0; j < 4; ++j) o[j] = acc[i][j] + bp2[tx * 4 + j];
    *reinterpret_cast<float4*>(X + (size_t)row * 64 + tx * 4) = make_float4(o[0], o[1], o[2], o[3]);
  }
}

// ---------------------------------------------------------------------------
// prez: G1[dir][row][c] = x@[Wz|Wr](top) + h@[Wz|Wr](bot)   (M=16384,N=128,K=128)
// tile 64x128, 256 thr, acc 4x8
// ---------------------------------------------------------------------------
__global__ __launch_bounds__(256) void prez_kernel(
    const float* __restrict__ x0p, const float* __restrict__ x1p,
    const float* __restrict__ h0p, const float* __restrict__ h1p,
    const float* __restrict__ WzF, const float* __restrict__ WzR,
    const float* __restrict__ WrF, const float* __restrict__ WrR,
    float* __restrict__ G1)
{
  __shared__ __align__(16) float As[8][68];
  __shared__ __align__(16) float Bs[8][132];
  const int tid = threadIdx.x;
  const int row0 = blockIdx.x * 64;
  const int dir  = blockIdx.z;
  const float* __restrict__ xs = dir ? x1p : x0p;
  const float* __restrict__ hs = dir ? h1p : h0p;
  const float* __restrict__ Wz = dir ? WzR : WzF;
  const float* __restrict__ Wr = dir ? WrR : WrF;
  float* __restrict__ G1d = G1 + (size_t)dir * ((size_t)ROWS * 128);

  const int tx = tid & 15, ty = tid >> 4;
  const int a_row = tid & 63, a_k0 = ((tid >> 6) & 1) * 4;
  const int b_kk = tid >> 5, b_f0 = (tid & 31) * 4;

  float acc[4][8] = {};
  for (int kt = 0; kt < 128; kt += 8) {
    float4 av = make_float4(0.f, 0.f, 0.f, 0.f);
    if (tid < 128) {
      const int kg = kt + a_k0;
      const float* src = (kg < 64) ? (xs + (size_t)(row0 + a_row) * 64 + kg)
                                   : (hs + (size_t)(row0 + a_row) * 64 + (kg - 64));
      av = *reinterpret_cast<const float4*>(src);
    }
    const int kgb = kt + b_kk;
    const float* wsrc = (b_f0 < 64) ? (Wz + (size_t)kgb * 64 + b_f0)
                                    : (Wr + (size_t)kgb * 64 + (b_f0 - 64));
    float4 bv = *reinterpret_cast<const float4*>(wsrc);
    __syncthreads();
    if (tid < 128) {
      As[a_k0 + 0][a_row] = av.x;
      As[a_k0 + 1][a_row] = av.y;
      As[a_k0 + 2][a_row] = av.z;
      As[a_k0 + 3][a_row] = av.w;
    }
    *reinterpret_cast<float4*>(&Bs[b_kk][b_f0]) = bv;
    __syncthreads();
#pragma unroll
    for (int kk = 0; kk < 8; ++kk) {
      const float4 a0 = *reinterpret_cast<const float4*>(&As[kk][ty * 4]);
      const float4 b0 = *reinterpret_cast<const float4*>(&Bs[kk][tx * 8]);
      const float4 b1 = *reinterpret_cast<const float4*>(&Bs[kk][tx * 8 + 4]);
      const float avv[4] = {a0.x, a0.y, a0.z, a0.w};
      const float bvv[8] = {b0.x, b0.y, b0.z, b0.w, b1.x, b1.y, b1.z, b1.w};
#pragma unroll
      for (int i = 0; i < 4; ++i)
#pragma unroll
        for (int j = 0; j < 8; ++j)
          acc[i][j] = fmaf(avv[i], bvv[j], acc[i][j]);
    }
  }
#pragma unroll
  for (int i = 0; i < 4; ++i) {
    float* p = G1d + (size_t)(row0 + ty * 4 + i) * 128 + tx * 8;
    *reinterpret_cast<float4*>(p)     = make_float4(acc[i][0], acc[i][1], acc[i][2], acc[i][3]);
    *reinterpret_cast<float4*>(p + 4) = make_float4(acc[i][4], acc[i][5], acc[i][6], acc[i][7]);
  }
}

// ---------------------------------------------------------------------------
// convzr: AG = adj @ G1 (K=1024), fused epilogue: z=sig(+bz), rh=sig(+br)*h
// tile 128x128, 512 thr = 2 K-streams of 256 (in-block split-K), 8x8 acc
// ---------------------------------------------------------------------------
__global__ __launch_bounds__(512) void convzr_kernel(
    const float* __restrict__ adj, const float* __restrict__ G1,
    const float* __restrict__ bzF, const float* __restrict__ bzR,
    const float* __restrict__ brF, const float* __restrict__ brR,
    const float* __restrict__ h0p, const float* __restrict__ h1p,
    float* __restrict__ zbuf, float* __restrict__ rhbuf)
{
  __shared__ __align__(16) float As[2][8][132];
  __shared__ __align__(16) float Bs[2][8][132];
  __shared__ __align__(16) float Red[128][132];
  const int tid = threadIdx.x;
  const int sub = tid >> 8;
  const int t   = tid & 255;
  const int n0  = blockIdx.x * 128;
  const int b   = blockIdx.y;
  const int dir = blockIdx.z;
  const float* __restrict__ bz = dir ? bzR : bzF;
  const float* __restrict__ br = dir ? brR : brF;
  const float* __restrict__ hb = dir ? h1p : h0p;
  const float* __restrict__ G1d = G1 + (size_t)dir * ((size_t)ROWS * 128);
  float* __restrict__ zb = zbuf  + (size_t)dir * ((size_t)ROWS * 64);
  float* __restrict__ rb = rhbuf + (size_t)dir * ((size_t)ROWS * 64);

  const int a_nl = t >> 1, a_k0 = (t & 1) * 4;
  const int b_kk = t >> 5, b_f0 = (t & 31) * 4;
  const int tx = t & 15, ty = t >> 4;
  const int kb = sub * 512;

  float acc[8][8] = {};
  const float* aptr = adj + (size_t)(n0 + a_nl) * Nn + kb + a_k0;
  const float* bptr = G1d + (size_t)(b * Nn + kb + b_kk) * 128 + b_f0;

  for (int kt = 0; kt < 512; kt += 8) {
    float4 av = *reinterpret_cast<const float4*>(aptr + kt);
    float4 bv = *reinterpret_cast<const float4*>(bptr + (size_t)kt * 128);
    __syncthreads();
    As[sub][a_k0 + 0][a_nl] = av.x;
    As[sub][a_k0 + 1][a_nl] = av.y;
    As[sub][a_k0 + 2][a_nl] = av.z;
    As[sub][a_k0 + 3][a_nl] = av.w;
    *reinterpret_cast<float4*>(&Bs[sub][b_kk][b_f0]) = bv;
    __syncthreads();
#pragma unroll
    for (int kk = 0; kk < 8; ++kk) {
      const float4 a0 = *reinterpret_cast<const float4*>(&As[sub][kk][ty * 8]);
      const float4 a1 = *reinterpret_cast<const float4*>(&As[sub][kk][ty * 8 + 4]);
      const float4 b0 = *reinterpret_cast<const float4*>(&Bs[sub][kk][tx * 8]);
      const float4 b1 = *reinterpret_cast<const float4*>(&Bs[sub][kk][tx * 8 + 4]);
      const float avv[8] = {a0.x, a0.y, a0.z, a0.w, a1.x, a1.y, a1.z, a1.w};
      const float bvv[8] = {b0.x, b0.y, b0.z, b0.w, b1.x, b1.y, b1.z, b1.w};
#pragma unroll
      for (int i = 0; i < 8; ++i)
#pragma unroll
        for (int j = 0; j < 8; ++j)
          acc[i][j] = fmaf(avv[i], bvv[j], acc[i][j]);
    }
  }
  __syncthreads();
  if (sub) {
#pragma unroll
    for (int i = 0; i < 8; ++i) {
      *reinterpret_cast<float4*>(&Red[ty * 8 + i][tx * 8])     = make_float4(acc[i][0], acc[i][1], acc[i][2], acc[i][3]);
      *reinterpret_cast<float4*>(&Red[ty * 8 + i][tx * 8 + 4]) = make_float4(acc[i][4], acc[i][5], acc[i][6], acc[i][7]);
    }
  }
  __syncthreads();
  if (!sub) {
#pragma unroll
    for (int i = 0; i < 8; ++i) {
      const float4 r0 = *reinterpret_cast<const float4*>(&Red[ty * 8 + i][tx * 8]);
      const float4 r1 = *reinterpret_cast<const float4*>(&Red[ty * 8 + i][tx * 8 + 4]);
      acc[i][0] += r0.x; acc[i][1] += r0.y; acc[i][2] += r0.z; acc[i][3] += r0.w;
      acc[i][4] += r1.x; acc[i][5] += r1.y; acc[i][6] += r1.z; acc[i][7] += r1.w;
    }
    const int rowg0 = b * Nn + n0;
    if (tx < 8) {
      const int c0 = tx * 8;
#pragma unroll
      for (int i = 0; i < 8; ++i) {
        const int row = rowg0 + ty * 8 + i;
        float o[8];
#pragma unroll
        for (int j = 0; j < 8; ++j) o[j] = sigmoidf_(acc[i][j] + bz[c0 + j]);
        float* p = zb + (size_t)row * 64 + c0;
        *reinterpret_cast<float4*>(p)     = make_float4(o[0], o[1], o[2], o[3]);
        *reinterpret_cast<float4*>(p + 4) = make_float4(o[4], o[5], o[6], o[7]);
      }
    } else {
      const int c0 = (tx - 8) * 8;
#pragma unroll
      for (int i = 0; i < 8; ++i) {
        const int row = rowg0 + ty * 8 + i;
        const float* hp = hb + (size_t)row * 64 + c0;
        const float4 h0 = *reinterpret_cast<const float4*>(hp);
        const float4 h1 = *reinterpret_cast<const float4*>(hp + 4);
        const float hh[8] = {h0.x, h0.y, h0.z, h0.w, h1.x, h1.y, h1.z, h1.w};
        float o[8];
#pragma unroll
        for (int j = 0; j < 8; ++j) o[j] = sigmoidf_(acc[i][j] + br[c0 + j]) * hh[j];
        float* p = rb + (size_t)row * 64 + c0;
        *reinterpret_cast<float4*>(p)     = make_float4(o[0], o[1], o[2], o[3]);
        *reinterpret_cast<float4*>(p + 4) = make_float4(o[4], o[5], o[6], o[7]);
      }
    }
  }
}

// ---------------------------------------------------------------------------
// prec: G2[dir][row][c] = x@Wc(top) + rh@Wc(bot)   (M=16384,N=64,K=128)
// tile 64x64, 256 thr, acc 4x4
// ---------------------------------------------------------------------------
__global__ __launch_bounds__(256) void prec_kernel(
    const float* __restrict__ x0p, const float* __restrict__ x1p,
    const float* __restrict__ rhbuf,
    const float* __restrict__ WcF, const float* __restrict__ WcR,
    float* __restrict__ G2)
{
  __shared__ __align__(16) float As[8][68];
  __shared__ __align__(16) float Bs[8][68];
  const int tid = threadIdx.x;
  const int row0 = blockIdx.x * 64;
  const int dir  = blockIdx.z;
  const float* __restrict__ xs = dir ? x1p : x0p;
  const float* __restrict__ rs = rhbuf + (size_t)dir * ((size_t)ROWS * 64);
  const float* __restrict__ Wc = dir ? WcR : WcF;
  float* __restrict__ G2d = G2 + (size_t)dir * ((size_t)ROWS * 64);

  const int tx = tid & 15, ty = tid >> 4;
  const int a_row = tid & 63, a_k0 = ((tid >> 6) & 1) * 4;
  const int b_kk = (tid >> 4) & 7, b_f0 = (tid & 15) * 4;

  float acc[4][4] = {};
  for (int kt = 0; kt < 128; kt += 8) {
    float4 av = make_float4(0.f, 0.f, 0.f, 0.f);
    float4 bv = make_float4(0.f, 0.f, 0.f, 0.f);
    if (tid < 128) {
      const int kg = kt + a_k0;
      const float* src = (kg < 64) ? (xs + (size_t)(row0 + a_row) * 64 + kg)
                                   : (rs + (size_t)(row0 + a_row) * 64 + (kg - 64));
      av = *reinterpret_cast<const float4*>(src);
      bv = *reinterpret_cast<const float4*>(Wc + (size_t)(kt + b_kk) * 64 + b_f0);
    }
    __syncthreads();
    if (tid < 128) {
      As[a_k0 + 0][a_row] = av.x;
      As[a_k0 + 1][a_row] = av.y;
      As[a_k0 + 2][a_row] = av.z;
      As[a_k0 + 3][a_row] = av.w;
      *reinterpret_cast<float4*>(&Bs[b_kk][b_f0]) = bv;
    }
    __syncthreads();
#pragma unroll
    for (int kk = 0; kk < 8; ++kk) {
      const float4 a0 = *reinterpret_cast<const float4*>(&As[kk][ty * 4]);
      const float4 b0 = *reinterpret_cast<const float4*>(&Bs[kk][tx * 4]);
      const float avv[4] = {a0.x, a0.y, a0.z, a0.w};
      const float bvv[4] = {b0.x, b0.y, b0.z, b0.w};
#pragma unroll
      for (int i = 0; i < 4; ++i)
#pragma unroll
        for (int j = 0; j < 4; ++j)
          acc[i][j] = fmaf(avv[i], bvv[j], acc[i][j]);
    }
  }
#pragma unroll
  for (int i = 0; i < 4; ++i) {
    float* p = G2d + (size_t)(row0 + ty * 4 + i) * 64 + tx * 4;
    *reinterpret_cast<float4*>(p) = make_float4(acc[i][0], acc[i][1], acc[i][2], acc[i][3]);
  }
}

// ---------------------------------------------------------------------------
// convc: AG2 = adj @ G2 (both dirs in one block: cols 0-63 dir0, 64-127 dir1)
// fused epilogue: c=tanh(+bc); h = z*h+(1-z)*c  (in place)
// tile 64(n) x 128(c), 512 thr = 2 K-streams, acc 4x8
// ---------------------------------------------------------------------------
__global__ __launch_bounds__(512) void convc_kernel(
    const float* __restrict__ adj, const float* __restrict__ G2,
    const float* __restrict__ bcF, const float* __restrict__ bcR,
    const float* __restrict__ zbuf,
    float* __restrict__ h0p, float* __restrict__ h1p)
{
  __shared__ __align__(16) float As[2][8][68];
  __shared__ __align__(16) float Bs[2][8][132];
  __shared__ __align__(16) float Red[64][132];
  const int tid = threadIdx.x;
  const int sub = tid >> 8;
  const int t   = tid & 255;
  const int n0  = blockIdx.x * 64;
  const int b   = blockIdx.y;
  const int kb  = sub * 512;
  const int tx = t & 15, ty = t >> 4;
  const int b_kk = t >> 5, b_f0 = (t & 31) * 4;
  const int a_row = t & 63, a_k0 = ((t >> 6) & 1) * 4;

  float acc[4][8] = {};
  const float* aptr = adj + (size_t)(n0 + a_row) * Nn + kb + a_k0;
  const float* bptr = G2 + (size_t)(b_f0 >> 6) * ((size_t)ROWS * 64)
                    + (size_t)(b * Nn + kb + b_kk) * 64 + (b_f0 & 63);

  for (int kt = 0; kt < 512; kt += 8) {
    float4 av = make_float4(0.f, 0.f, 0.f, 0.f);
    if (t < 128) av = *reinterpret_cast<const float4*>(aptr + kt);
    float4 bv = *reinterpret_cast<const float4*>(bptr + (size_t)kt * 64);
    __syncthreads();
    if (t < 128) {
      As[sub][a_k0 + 0][a_row] = av.x;
      As[sub][a_k0 + 1][a_row] = av.y;
      As[sub][a_k0 + 2][a_row] = av.z;
      As[sub][a_k0 + 3][a_row] = av.w;
    }
    *reinterpret_cast<float4*>(&Bs[sub][b_kk][b_f0]) = bv;
    __syncthreads();
#pragma unroll
    for (int kk = 0; kk < 8; ++kk) {
      const float4 a0 = *reinterpret_cast<const float4*>(&As[sub][kk][ty * 4]);
      const float4 b0 = *reinterpret_cast<const float4*>(&Bs[sub][kk][tx * 8]);
      const float4 b1 = *reinterpret_cast<const float4*>(&Bs[sub][kk][tx * 8 + 4]);
      const float avv[4] = {a0.x, a0.y, a0.z, a0.w};
      const float bvv[8] = {b0.x, b0.y, b0.z, b0.w, b1.x, b1.y, b1.z, b1.w};
#pragma unroll
      for (int i = 0; i < 4; ++i)
#pragma unroll
        for (int j = 0; j < 8; ++j)
          acc[i][j] = fmaf(avv[i], bvv[j], acc[i][j]);
    }
  }
  __syncthreads();
  if (sub) {
#pragma unroll
    for (int i = 0; i < 4; ++i) {
      *reinterpret_cast<float4*>(&Red[ty * 4 + i][tx * 8])     = make_float4(acc[i][0], acc[i][1], acc[i][2], acc[i][3]);
      *reinterpret_cast<float4*>(&Red[ty * 4 + i][tx * 8 + 4]) = make_float4(acc[i][4], acc[i][5], acc[i][6], acc[i][7]);
    }
  }
  __syncthreads();
  if (!sub) {
#pragma unroll
    for (int i = 0; i < 4; ++i) {
      const float4 r0 = *reinterpret_cast<const float4*>(&Red[ty * 4 + i][tx * 8]);
      const float4 r1 = *reinterpret_cast<const float4*>(&Red[ty * 4 + i][tx * 8 + 4]);
      acc[i][0] += r0.x; acc[i][1] += r0.y; acc[i][2] += r0.z; acc[i][3] += r0.w;
      acc[i][4] += r1.x; acc[i][5] += r1.y; acc[i][6] += r1.z; acc[i][7] += r1.w;
    }
    const int dirc = tx >> 3;
    const int hc0  = (tx & 7) * 8;
    const float* __restrict__ bc = dirc ? bcR : bcF;
    const float* __restrict__ zb = zbuf + (size_t)dirc * ((size_t)ROWS * 64);
    float* __restrict__ hb = dirc ? h1p : h0p;
#pragma unroll
    for (int i = 0; i < 4; ++i) {
      const int row = b * Nn + n0 + ty * 4 + i;
      float* hp = hb + (size_t)row * 64 + hc0;
      const float* zp = zb + (size_t)row * 64 + hc0;
      const float4 h0 = *reinterpret_cast<const float4*>(hp);
      const float4 h1 = *reinterpret_cast<const float4*>(hp + 4);
      const float4 z0 = *reinterpret_cast<const float4*>(zp);
      const float4 z1 = *reinterpret_cast<const float4*>(zp + 4);
      const float hh[8] = {h0.x, h0.y, h0.z, h0.w, h1.x, h1.y, h1.z, h1.w};
      const float zz[8] = {z0.x, z0.y, z0.z, z0.w, z1.x, z1.y, z1.z, z1.w};
      float o[8];
#pragma unroll
      for (int j = 0; j < 8; ++j) {
        float c = tanhf(acc[i][j] + bc[hc0 + j]);
        o[j] = zz[j] * hh[j] + (1.0f - zz[j]) * c;
      }
      *reinterpret_cast<float4*>(hp)     = make_float4(o[0], o[1], o[2], o[3]);
      *reinterpret_cast<float4*>(hp + 4) = make_float4(o[4], o[5], o[6], o[7]);
    }
  }
}

// ---------------------------------------------------------------------------
// Decoder stage 1: D1 = relu(concat(hid_f,hid_r) @ Wd1 + bd1)
// ---------------------------------------------------------------------------
__global__ __launch_bounds__(256) void dec1_kernel(
    const float* __restrict__ Hws,
    const float* __restrict__ Wd1, const float* __restrict__ bd1,
    float* __restrict__ D1)
{
  __shared__ __align__(16) float As[8][132];
  __shared__ __align__(16) float Bs[8][132];
  const int tid = threadIdx.x;
  const int row0 = blockIdx.x * 128;
  const int cb   = blockIdx.y * 128;
  const int a_nl = tid >> 1, a_k0 = (tid & 1) * 4;
  const int b_kk = tid >> 5, b_f0 = (tid & 31) * 4;
  const int tx = tid & 15, ty = tid >> 4;

  float acc[8][8] = {};
  const int arow = row0 + a_nl;
  const int l  = arow >> 14;
  const int ri = arow & 16383;

  for (int kt = 0; kt < 128; kt += 8) {
    const int k0 = kt + a_k0;
    const float* abase = (k0 < 64)
        ? (Hws + (size_t)l * HSZ + (size_t)ri * 64 + k0)
        : (Hws + (size_t)(2 + l) * HSZ + (size_t)ri * 64 + (k0 - 64));
    float4 av = *reinterpret_cast<const float4*>(abase);
    float4 bv = *reinterpret_cast<const float4*>(Wd1 + (size_t)(kt + b_kk) * 256 + cb + b_f0);
    __syncthreads();
    As[a_k0 + 0][a_nl] = av.x;
    As[a_k0 + 1][a_nl] = av.y;
    As[a_k0 + 2][a_nl] = av.z;
    As[a_k0 + 3][a_nl] = av.w;
    *reinterpret_cast<float4*>(&Bs[b_kk][b_f0]) = bv;
    __syncthreads();
#pragma unroll
    for (int kk = 0; kk < 8; ++kk) {
      const float4 a0 = *reinterpret_cast<const float4*>(&As[kk][ty * 8]);
      const float4 a1 = *reinterpret_cast<const float4*>(&As[kk][ty * 8 + 4]);
      const float4 b0 = *reinterpret_cast<const float4*>(&Bs[kk][tx * 8]);
      const float4 b1 = *reinterpret_cast<const float4*>(&Bs[kk][tx * 8 + 4]);
      const float avv[8] = {a0.x, a0.y, a0.z, a0.w, a1.x, a1.y, a1.z, a1.w};
      const float bvv[8] = {b0.x, b0.y, b0.z, b0.w, b1.x, b1.y, b1.z, b1.w};
#pragma unroll
      for (int i = 0; i < 8; ++i)
#pragma unroll
        for (int j = 0; j < 8; ++j)
          acc[i][j] = fmaf(avv[i], bvv[j], acc[i][j]);
    }
  }
#pragma unroll
  for (int i = 0; i < 8; ++i) {
    const int row = row0 + ty * 8 + i;
    float* p = D1 + (size_t)row * 256 + cb + tx * 8;
    float o[8];
#pragma unroll
    for (int j = 0; j < 8; ++j) o[j] = fmaxf(acc[i][j] + bd1[cb + tx * 8 + j], 0.0f);
    *reinterpret_cast<float4*>(p)     = make_float4(o[0], o[1], o[2], o[3]);
    *reinterpret_cast<float4*>(p + 4) = make_float4(o[4], o[5], o[6], o[7]);
  }
}

// ---------------------------------------------------------------------------
// Decoder stage 2
// ---------------------------------------------------------------------------
__global__ __launch_bounds__(256) void dec2_kernel(
    const float* __restrict__ D1, const float* __restrict__ Wd2,
    const float* __restrict__ bd2, float* __restrict__ out)
{
  __shared__ __align__(16) float As[8][132];
  __shared__ __align__(16) float Bs[8][68];
  const int tid = threadIdx.x;
  const int row0 = blockIdx.x * 128;
  const int a_nl = tid >> 1, a_k0 = (tid & 1) * 4;
  const int w_kk = tid >> 4, w_c0 = (tid & 15) * 4;
  const int tx = tid & 15, ty = tid >> 4;

  float acc[8][4] = {};
  const float* aptr = D1 + (size_t)(row0 + a_nl) * 256 + a_k0;

  for (int kt = 0; kt < 256; kt += 8) {
    float4 av = *reinterpret_cast<const float4*>(aptr + kt);
    float4 wv = make_float4(0.f, 0.f, 0.f, 0.f);
    if (tid < 128) wv = *reinterpret_cast<const float4*>(Wd2 + (size_t)(kt + w_kk) * 64 + w_c0);
    __syncthreads();
    As[a_k0 + 0][a_nl] = av.x;
    As[a_k0 + 1][a_nl] = av.y;
    As[a_k0 + 2][a_nl] = av.z;
    As[a_k0 + 3][a_nl] = av.w;
    if (tid < 128) *reinterpret_cast<float4*>(&Bs[w_kk][w_c0]) = wv;
    __syncthreads();
#pragma unroll
    for (int kk = 0; kk < 8; ++kk) {
      const float4 a0 = *reinterpret_cast<const float4*>(&As[kk][ty * 8]);
      const float4 a1 = *reinterpret_cast<const float4*>(&As[kk][ty * 8 + 4]);
      const float4 b0 = *reinterpret_cast<const float4*>(&Bs[kk][tx * 4]);
      const float avv[8] = {a0.x, a0.y, a0.z, a0.w, a1.x, a1.y, a1.z, a1.w};
      const float bvv[4] = {b0.x, b0.y, b0.z, b0.w};
#pragma unroll
      for (int i = 0; i < 8; ++i)
#pragma unroll
        for (int j = 0; j < 4; ++j)
          acc[i][j] = fmaf(avv[i], bvv[j], acc[i][j]);
    }
  }
#pragma unroll
  for (int i = 0; i < 8; ++i) {
    const int row = row0 + ty * 8 + i;
    float o[4];
#pragma unroll
    for (int j = 0; j < 4; ++j) o[j] = acc[i][j] + bd2[tx * 4 + j];
    *reinterpret_cast<float4*>(out + (size_t)row * 64 + tx * 4) = make_float4(o[0], o[1], o[2], o[3]);
  }
}

// ---------------------------------------------------------------------------
// Host driver
// ---------------------------------------------------------------------------
extern "C" void kernel_launch(void* const* d_in, const int* in_sizes, int n_in,
                              void* d_out, int out_size, void* d_ws, size_t ws_size,
                              hipStream_t stream)
{
  (void)in_sizes; (void)n_in; (void)out_size; (void)ws_size;
  const float* inputs = (const float*)d_in[0];
  const float* mask   = (const float*)d_in[1];
  const float* adj    = (const float*)d_in[2];
  const float* Wp1    = (const float*)d_in[3];
  const float* bp1    = (const float*)d_in[4];
  const float* Wp2    = (const float*)d_in[5];
  const float* bp2    = (const float*)d_in[6];
  const float* Wz_f   = (const float*)d_in[7];
  const float* Wr_f   = (const float*)d_in[8];
  const float* Wc_f   = (const float*)d_in[9];
  const float* bz_f   = (const float*)d_in[10];
  const float* br_f   = (const float*)d_in[11];
  const float* bc_f   = (const float*)d_in[12];
  const float* Wz_r   = (const float*)d_in[13];
  const float* Wr_r   = (const float*)d_in[14];
  const float* Wc_r   = (const float*)d_in[15];
  const float* bz_r   = (const float*)d_in[16];
  const float* br_r   = (const float*)d_in[17];
  const float* bc_r   = (const float*)d_in[18];
  const float* Wd1    = (const float*)d_in[19];
  const float* bd1    = (const float*)d_in[20];
  const float* Wd2    = (const float*)d_in[21];
  const float* bd2    = (const float*)d_in[22];

  float* ws = (float*)d_ws;
  float* S0 = ws;                                   // 196608
  float* X  = S0 + TOT;                             // TOT*64
  float* H  = X + (size_t)TOT * 64;                 // 4*HSZ   [dir*2+l]
  float* Z  = H + 4 * HSZ;                          // 2*HSZ
  float* RH = Z + 2 * HSZ;                          // 2*HSZ
  float* U  = RH + 2 * HSZ;                         // union region
  float* G1 = U;                                    // 2*ROWS*128
  float* G2 = U + 2 * (size_t)ROWS * 128;           // 2*ROWS*64
  float* D1 = U;                                    // 32768*256 (after loop, aliases G1/G2)

  hipMemsetAsync(H, 0, 4 * HSZ * sizeof(float), stream);

  seq_kernel<<<dim3((HALF + 255) / 256), 256, 0, stream>>>(inputs, S0);
  proj_kernel<<<dim3(TOT / 128), 256, 0, stream>>>(S0, mask, Wp1, bp1, Wp2, bp2, X);

  for (int t = 0; t < Tn; ++t) {
    for (int l = 0; l < Ln; ++l) {
      const float* x0 = (l == 0) ? (X + (size_t)t * HSZ) : H;
      const float* x1 = (l == 0) ? (X + (size_t)(Tn - 1 - t) * HSZ) : (H + 2 * HSZ);
      float* h0 = H + (size_t)l * HSZ;
      float* h1 = H + (size_t)(2 + l) * HSZ;

      prez_kernel<<<dim3(256, 1, 2), 256, 0, stream>>>(
          x0, x1, h0, h1,
          Wz_f + l * 8192, Wz_r + l * 8192, Wr_f + l * 8192, Wr_r + l * 8192, G1);
      convzr_kernel<<<dim3(8, 16, 2), 512, 0, stream>>>(
          adj, G1, bz_f + l * 64, bz_r + l * 64, br_f + l * 64, br_r + l * 64,
          h0, h1, Z, RH);
      prec_kernel<<<dim3(256, 1, 2), 256, 0, stream>>>(
          x0, x1, RH, Wc_f + l * 8192, Wc_r + l * 8192, G2);
      convc_kernel<<<dim3(16, 16), 512, 0, stream>>>(
          adj, G2, bc_f + l * 64, bc_r + l * 64, Z, h0, h1);
    }
  }

  dec1_kernel<<<dim3(256, 2), 256, 0, stream>>>(H, Wd1, bd1, D1);
  dec2_kernel<<<dim3(256, 1), 256, 0, stream>>>(D1, Wd2, bd2, (float*)d_out);
}

// Round 3
// 3738.316 us; speedup vs baseline: 2.3355x; 1.5693x over previous
//
#include <hip/hip_runtime.h>
#include <cstdint>
#include <cstddef>

constexpr int Tn = 12, Bn = 16, Nn = 1024, Hn = 64, Ln = 2;
constexpr int ROWS = Bn * Nn;                 // 16384
constexpr int TOT  = Tn * Bn * Nn;            // 196608
constexpr int HALF = TOT / 2;
constexpr size_t HSZ = (size_t)Bn * Nn * Hn;  // 1048576 floats

#define DEVFN __device__ __forceinline__

typedef __attribute__((ext_vector_type(4))) float f32x4;
typedef __attribute__((ext_vector_type(8))) __bf16 bf16x8;
typedef unsigned short ushort_t;

// ---------------------------------------------------------------------------
// bf16 split helpers (RNE)
// ---------------------------------------------------------------------------
DEVFN ushort_t f2bf_rne(float f) {
  uint32_t u = __float_as_uint(f);
  uint32_t r = u + 0x7FFFu + ((u >> 16) & 1u);
  return (ushort_t)(r >> 16);
}
DEVFN float bf2f(ushort_t h) { return __uint_as_float(((uint32_t)h) << 16); }

// ---------------------------------------------------------------------------
// threefry2x32 (key 0,42) + XLA-exact normal
// ---------------------------------------------------------------------------
DEVFN uint32_t rotl32(uint32_t v, int d) { return (v << d) | (v >> (32 - d)); }

DEVFN void threefry_0_42(uint32_t& x0, uint32_t& x1) {
  const uint32_t k0 = 0u, k1 = 42u, k2 = k0 ^ k1 ^ 0x1BD11BDAu;
  x0 += k0; x1 += k1;
#define TFR(r) { x0 += x1; x1 = rotl32(x1, r); x1 ^= x0; }
  TFR(13) TFR(15) TFR(26) TFR(6)
  x0 += k1; x1 += k2 + 1u;
  TFR(17) TFR(29) TFR(16) TFR(24)
  x0 += k2; x1 += k0 + 2u;
  TFR(13) TFR(15) TFR(26) TFR(6)
  x0 += k0; x1 += k1 + 3u;
  TFR(17) TFR(29) TFR(16) TFR(24)
  x0 += k1; x1 += k2 + 4u;
  TFR(13) TFR(15) TFR(26) TFR(6)
  x0 += k2; x1 += k0 + 5u;
#undef TFR
}

DEVFN float erfinv32(float x) {
  float w = -log1pf(-x * x);
  float p;
  if (w < 5.0f) {
    w = w - 2.5f;
    p = 2.81022636e-08f;
    p = fmaf(p, w, 3.43273939e-07f);
    p = fmaf(p, w, -3.5233877e-06f);
    p = fmaf(p, w, -4.39150654e-06f);
    p = fmaf(p, w, 0.00021858087f);
    p = fmaf(p, w, -0.00125372503f);
    p = fmaf(p, w, -0.00417768164f);
    p = fmaf(p, w, 0.246640727f);
    p = fmaf(p, w, 1.50140941f);
  } else {
    w = sqrtf(w) - 3.0f;
    p = -0.000200214257f;
    p = fmaf(p, w, 0.000100950558f);
    p = fmaf(p, w, 0.00134934322f);
    p = fmaf(p, w, -0.00367342844f);
    p = fmaf(p, w, 0.00573950773f);
    p = fmaf(p, w, -0.0076224613f);
    p = fmaf(p, w, 0.00943887047f);
    p = fmaf(p, w, 1.00167406f);
    p = fmaf(p, w, 2.83297682f);
  }
  return p * x;
}

DEVFN float bits_to_normal(uint32_t bits) {
  float f = __uint_as_float((bits >> 9) | 0x3f800000u) - 1.0f;
  const float lo = -0.99999994f;
  float u = fmaf(f, 2.0f, lo);
  u = fmaxf(lo, u);
  return 1.41421356237f * erfinv32(u);
}

__global__ __launch_bounds__(256) void seq_kernel(const float* __restrict__ inputs,
                                                  float* __restrict__ s0) {
  int i = blockIdx.x * 256 + threadIdx.x;
  if (i >= HALF) return;
  uint32_t x0 = (uint32_t)i, x1 = (uint32_t)(i + HALF);
  threefry_0_42(x0, x1);
  s0[i]        = inputs[i]        + 0.01f * bits_to_normal(x0);
  s0[i + HALF] = inputs[i + HALF] + 0.01f * bits_to_normal(x1);
}

DEVFN float sigmoidf_(float x) { return 1.0f / (1.0f + expf(-x)); }

// ---------------------------------------------------------------------------
// adj -> bf16 hi/lo planes (once per call)
// ---------------------------------------------------------------------------
__global__ __launch_bounds__(256) void adjsplit_kernel(const float* __restrict__ adj,
                                                       ushort_t* __restrict__ hi,
                                                       ushort_t* __restrict__ lo) {
  int i = blockIdx.x * 256 + threadIdx.x;   // grid 4096 -> 1M
  float v = adj[i];
  ushort_t h = f2bf_rne(v);
  float r = v - bf2f(h);
  hi[i] = h;
  lo[i] = f2bf_rne(r);
}

// ---------------------------------------------------------------------------
// Projection: X[row][h] = relu(s0*Wp1[0]+s1*Wp1[1]+bp1) @ Wp2 + bp2
// ---------------------------------------------------------------------------
__global__ __launch_bounds__(256) void proj_kernel(
    const float* __restrict__ s0g, const float* __restrict__ s1g,
    const float* __restrict__ Wp1, const float* __restrict__ bp1,
    const float* __restrict__ Wp2, const float* __restrict__ bp2,
    float* __restrict__ X)
{
  __shared__ __align__(16) float As[8][132];
  __shared__ __align__(16) float Bs[8][68];
  __shared__ float W0[256], W1[256], Wb[256], Ss0[128], Ss1[128];
  const int tid = threadIdx.x;
  const int row0 = blockIdx.x * 128;
  W0[tid] = Wp1[tid];
  W1[tid] = Wp1[256 + tid];
  Wb[tid] = bp1[tid];
  if (tid < 128) { Ss0[tid] = s0g[row0 + tid]; Ss1[tid] = s1g[row0 + tid]; }
  __syncthreads();

  const int a_nl = tid >> 1, a_kb = (tid & 1) * 4;
  const int w_kk = tid >> 4, w_c0 = (tid & 15) * 4;
  const int tx = tid & 15, ty = tid >> 4;
  const float sv0 = Ss0[a_nl], sv1 = Ss1[a_nl];

  float acc[8][4] = {};
  for (int kt = 0; kt < 256; kt += 8) {
    float4 wv = make_float4(0.f, 0.f, 0.f, 0.f);
    if (tid < 128) wv = *reinterpret_cast<const float4*>(Wp2 + (size_t)(kt + w_kk) * 64 + w_c0);
    __syncthreads();
#pragma unroll
    for (int u = 0; u < 4; ++u) {
      const int p = kt + a_kb + u;
      float v = fmaf(sv0, W0[p], fmaf(sv1, W1[p], Wb[p]));
      As[a_kb + u][a_nl] = fmaxf(v, 0.0f);
    }
    if (tid < 128) *reinterpret_cast<float4*>(&Bs[w_kk][w_c0]) = wv;
    __syncthreads();
#pragma unroll
    for (int kk = 0; kk < 8; ++kk) {
      const float4 a0 = *reinterpret_cast<const float4*>(&As[kk][ty * 8]);
      const float4 a1 = *reinterpret_cast<const float4*>(&As[kk][ty * 8 + 4]);
      const float4 b0 = *reinterpret_cast<const float4*>(&Bs[kk][tx * 4]);
      const float avv[8] = {a0.x, a0.y, a0.z, a0.w, a1.x, a1.y, a1.z, a1.w};
      const float bvv[4] = {b0.x, b0.y, b0.z, b0.w};
#pragma unroll
      for (int i = 0; i < 8; ++i)
#pragma unroll
        for (int j = 0; j < 4; ++j)
          acc[i][j] = fmaf(avv[i], bvv[j], acc[i][j]);
    }
  }
#pragma unroll
  for (int i = 0; i < 8; ++i) {
    const int row = row0 + ty * 8 + i;
    float o[4];
#pragma unroll
    for (int j = 0; j < 4; ++j) o[j] = acc[i][j] + bp2[tx * 4 + j];
    *reinterpret_cast<float4*>(X + (size_t)row * 64 + tx * 4) = make_float4(o[0], o[1], o[2], o[3]);
  }
}

// ---------------------------------------------------------------------------
// prez: G1t[dir][b][c:128][m:1024] (bf16 hi/lo) = transpose(xh @ [Wz|Wr])
// tile 64(m) x 128(c), fp32 GEMM + LDS-transpose + split epilogue
// ---------------------------------------------------------------------------
__global__ __launch_bounds__(256) void prez_kernel(
    const float* __restrict__ x0p, const float* __restrict__ x1p,
    const float* __restrict__ h0p, const float* __restrict__ h1p,
    const float* __restrict__ WzF, const float* __restrict__ WzR,
    const float* __restrict__ WrF, const float* __restrict__ WrR,
    ushort_t* __restrict__ G1tH, ushort_t* __restrict__ G1tL)
{
  __shared__ __align__(16) float As[8][68];
  __shared__ __align__(16) float Bs[8][132];
  __shared__ __align__(16) float T[128][73];
  const int tid = threadIdx.x;
  const int row0 = blockIdx.x * 64;
  const int dir  = blockIdx.z;
  const int b    = row0 >> 10;
  const int nloc = row0 & 1023;
  const float* __restrict__ xs = dir ? x1p : x0p;
  const float* __restrict__ hs = dir ? h1p : h0p;
  const float* __restrict__ Wz = dir ? WzR : WzF;
  const float* __restrict__ Wr = dir ? WrR : WrF;

  const int tx = tid & 15, ty = tid >> 4;
  const int a_row = tid & 63, a_k0 = ((tid >> 6) & 1) * 4;
  const int b_kk = tid >> 5, b_f0 = (tid & 31) * 4;

  float acc[4][8] = {};
  for (int kt = 0; kt < 128; kt += 8) {
    float4 av = make_float4(0.f, 0.f, 0.f, 0.f);
    if (tid < 128) {
      const int kg = kt + a_k0;
      const float* src = (kg < 64) ? (xs + (size_t)(row0 + a_row) * 64 + kg)
                                   : (hs + (size_t)(row0 + a_row) * 64 + (kg - 64));
      av = *reinterpret_cast<const float4*>(src);
    }
    const int kgb = kt + b_kk;
    const float* wsrc = (b_f0 < 64) ? (Wz + (size_t)kgb * 64 + b_f0)
                                    : (Wr + (size_t)kgb * 64 + (b_f0 - 64));
    float4 bv = *reinterpret_cast<const float4*>(wsrc);
    __syncthreads();
    if (tid < 128) {
      As[a_k0 + 0][a_row] = av.x;
      As[a_k0 + 1][a_row] = av.y;
      As[a_k0 + 2][a_row] = av.z;
      As[a_k0 + 3][a_row] = av.w;
    }
    *reinterpret_cast<float4*>(&Bs[b_kk][b_f0]) = bv;
    __syncthreads();
#pragma unroll
    for (int kk = 0; kk < 8; ++kk) {
      const float4 a0 = *reinterpret_cast<const float4*>(&As[kk][ty * 4]);
      const float4 b0 = *reinterpret_cast<const float4*>(&Bs[kk][tx * 8]);
      const float4 b1 = *reinterpret_cast<const float4*>(&Bs[kk][tx * 8 + 4]);
      const float avv[4] = {a0.x, a0.y, a0.z, a0.w};
      const float bvv[8] = {b0.x, b0.y, b0.z, b0.w, b1.x, b1.y, b1.z, b1.w};
#pragma unroll
      for (int i = 0; i < 4; ++i)
#pragma unroll
        for (int j = 0; j < 8; ++j)
          acc[i][j] = fmaf(avv[i], bvv[j], acc[i][j]);
    }
  }
  // transpose via LDS: T[c][m_local]
  __syncthreads();
#pragma unroll
  for (int i = 0; i < 4; ++i)
#pragma unroll
    for (int j = 0; j < 8; ++j)
      T[tx * 8 + j][ty * 4 + i] = acc[i][j];
  __syncthreads();
  {
    const int c = tid >> 1, mc = (tid & 1) * 32;
    alignas(16) ushort_t hsv[32], lsv[32];
#pragma unroll
    for (int k = 0; k < 32; ++k) {
      float v = T[c][mc + k];
      ushort_t h = f2bf_rne(v);
      hsv[k] = h;
      lsv[k] = f2bf_rne(v - bf2f(h));
    }
    size_t base = ((size_t)(dir * 16 + b) * 128 + c) * 1024 + nloc + mc;
#pragma unroll
    for (int q = 0; q < 4; ++q) {
      *reinterpret_cast<uint4*>(G1tH + base + q * 8) = *reinterpret_cast<uint4*>(&hsv[q * 8]);
      *reinterpret_cast<uint4*>(G1tL + base + q * 8) = *reinterpret_cast<uint4*>(&lsv[q * 8]);
    }
  }
}

// ---------------------------------------------------------------------------
// prec: G2t[b][dir*64+c][m:1024] (bf16 hi/lo) = transpose([x|r*h] @ Wc)
// ---------------------------------------------------------------------------
__global__ __launch_bounds__(256) void prec_kernel(
    const float* __restrict__ x0p, const float* __restrict__ x1p,
    const float* __restrict__ rhbuf,
    const float* __restrict__ WcF, const float* __restrict__ WcR,
    ushort_t* __restrict__ G2tH, ushort_t* __restrict__ G2tL)
{
  __shared__ __align__(16) float As[8][68];
  __shared__ __align__(16) float Bs[8][68];
  __shared__ __align__(16) float T[64][73];
  const int tid = threadIdx.x;
  const int row0 = blockIdx.x * 64;
  const int dir  = blockIdx.z;
  const int b    = row0 >> 10;
  const int nloc = row0 & 1023;
  const float* __restrict__ xs = dir ? x1p : x0p;
  const float* __restrict__ rs = rhbuf + (size_t)dir * ((size_t)ROWS * 64);
  const float* __restrict__ Wc = dir ? WcR : WcF;

  const int tx = tid & 15, ty = tid >> 4;
  const int a_row = tid & 63, a_k0 = ((tid >> 6) & 1) * 4;
  const int b_kk = (tid >> 4) & 7, b_f0 = (tid & 15) * 4;

  float acc[4][4] = {};
  for (int kt = 0; kt < 128; kt += 8) {
    float4 av = make_float4(0.f, 0.f, 0.f, 0.f);
    float4 bv = make_float4(0.f, 0.f, 0.f, 0.f);
    if (tid < 128) {
      const int kg = kt + a_k0;
      const float* src = (kg < 64) ? (xs + (size_t)(row0 + a_row) * 64 + kg)
                                   : (rs + (size_t)(row0 + a_row) * 64 + (kg - 64));
      av = *reinterpret_cast<const float4*>(src);
      bv = *reinterpret_cast<const float4*>(Wc + (size_t)(kt + b_kk) * 64 + b_f0);
    }
    __syncthreads();
    if (tid < 128) {
      As[a_k0 + 0][a_row] = av.x;
      As[a_k0 + 1][a_row] = av.y;
      As[a_k0 + 2][a_row] = av.z;
      As[a_k0 + 3][a_row] = av.w;
      *reinterpret_cast<float4*>(&Bs[b_kk][b_f0]) = bv;
    }
    __syncthreads();
#pragma unroll
    for (int kk = 0; kk < 8; ++kk) {
      const float4 a0 = *reinterpret_cast<const float4*>(&As[kk][ty * 4]);
      const float4 b0 = *reinterpret_cast<const float4*>(&Bs[kk][tx * 4]);
      const float avv[4] = {a0.x, a0.y, a0.z, a0.w};
      const float bvv[4] = {b0.x, b0.y, b0.z, b0.w};
#pragma unroll
      for (int i = 0; i < 4; ++i)
#pragma unroll
        for (int j = 0; j < 4; ++j)
          acc[i][j] = fmaf(avv[i], bvv[j], acc[i][j]);
    }
  }
  __syncthreads();
#pragma unroll
  for (int i = 0; i < 4; ++i)
#pragma unroll
    for (int j = 0; j < 4; ++j)
      T[tx * 4 + j][ty * 4 + i] = acc[i][j];
  __syncthreads();
  {
    const int c = tid >> 2, mc = (tid & 3) * 16;
    alignas(16) ushort_t hsv[16], lsv[16];
#pragma unroll
    for (int k = 0; k < 16; ++k) {
      float v = T[c][mc + k];
      ushort_t h = f2bf_rne(v);
      hsv[k] = h;
      lsv[k] = f2bf_rne(v - bf2f(h));
    }
    size_t base = ((size_t)b * 128 + (size_t)dir * 64 + c) * 1024 + nloc + mc;
#pragma unroll
    for (int q = 0; q < 2; ++q) {
      *reinterpret_cast<uint4*>(G2tH + base + q * 8) = *reinterpret_cast<uint4*>(&hsv[q * 8]);
      *reinterpret_cast<uint4*>(G2tL + base + q * 8) = *reinterpret_cast<uint4*>(&lsv[q * 8]);
    }
  }
}

// ---------------------------------------------------------------------------
// conv_mfma: AG[n][c] = sum_m adj[n][m] * G[m][c] via split-bf16 MFMA
// block 128(n) x 128(c), 4 waves of 64x64 (4x4 tiles of 16x16x32), K-step 32.
// EPI=0 (convzr): cols 0-63 -> z=sig(+bz); 64-127 -> rh=sig(+br)*h  (per dir=blockIdx.z)
// EPI=1 (convc):  cols 0-63 dir0, 64-127 dir1: c=tanh(+bc); h=z*h+(1-z)*c in place
// ---------------------------------------------------------------------------
template<int EPI>
__global__ __launch_bounds__(256) void conv_mfma(
    const ushort_t* __restrict__ adjHi, const ushort_t* __restrict__ adjLo,
    const ushort_t* __restrict__ BtH,  const ushort_t* __restrict__ BtL,
    const float* __restrict__ c0F, const float* __restrict__ c0R,
    const float* __restrict__ c1F, const float* __restrict__ c1R,
    float* __restrict__ zbuf, float* __restrict__ rhb,
    float* __restrict__ h0, float* __restrict__ h1)
{
  __shared__ ushort_t Ah[128][40], Al[128][40], Bh[128][40], Bl[128][40];
  const int tid = threadIdx.x;
  const int n0  = blockIdx.x * 128;
  const int b   = blockIdx.y;
  const int dir = blockIdx.z;

  // B-plane base for this block
  const size_t boff = (EPI == 0) ? ((size_t)(dir * 16 + b) * 128) * 1024
                                 : ((size_t)b * 128) * 1024;

  const int r0 = tid >> 2, ch = tid & 3;
  const ushort_t* aHp = adjHi + (size_t)(n0 + r0) * 1024 + ch * 8;
  const ushort_t* aLp = adjLo + (size_t)(n0 + r0) * 1024 + ch * 8;
  const ushort_t* bHp = BtH + boff + (size_t)r0 * 1024 + ch * 8;
  const ushort_t* bLp = BtL + boff + (size_t)r0 * 1024 + ch * 8;
  const size_t R64 = (size_t)64 * 1024;

  f32x4 acc[4][4];
#pragma unroll
  for (int i = 0; i < 4; ++i)
#pragma unroll
    for (int j = 0; j < 4; ++j) acc[i][j] = (f32x4)0.0f;

  const int lane = tid & 63, wave = tid >> 6;
  const int wr = (wave >> 1) * 64, wc = (wave & 1) * 64;
  const int lm = lane & 15, q8 = (lane >> 4) * 8;

  uint4 va0 = *reinterpret_cast<const uint4*>(aHp);
  uint4 va1 = *reinterpret_cast<const uint4*>(aHp + R64);
  uint4 vl0 = *reinterpret_cast<const uint4*>(aLp);
  uint4 vl1 = *reinterpret_cast<const uint4*>(aLp + R64);
  uint4 vb0 = *reinterpret_cast<const uint4*>(bHp);
  uint4 vb1 = *reinterpret_cast<const uint4*>(bHp + R64);
  uint4 vc0 = *reinterpret_cast<const uint4*>(bLp);
  uint4 vc1 = *reinterpret_cast<const uint4*>(bLp + R64);

  for (int kt = 0; kt < 32; ++kt) {
    __syncthreads();
    *reinterpret_cast<uint4*>(&Ah[r0][ch * 8])      = va0;
    *reinterpret_cast<uint4*>(&Ah[r0 + 64][ch * 8]) = va1;
    *reinterpret_cast<uint4*>(&Al[r0][ch * 8])      = vl0;
    *reinterpret_cast<uint4*>(&Al[r0 + 64][ch * 8]) = vl1;
    *reinterpret_cast<uint4*>(&Bh[r0][ch * 8])      = vb0;
    *reinterpret_cast<uint4*>(&Bh[r0 + 64][ch * 8]) = vb1;
    *reinterpret_cast<uint4*>(&Bl[r0][ch * 8])      = vc0;
    *reinterpret_cast<uint4*>(&Bl[r0 + 64][ch * 8]) = vc1;
    __syncthreads();
    if (kt < 31) {
      aHp += 32; aLp += 32; bHp += 32; bLp += 32;
      va0 = *reinterpret_cast<const uint4*>(aHp);
      va1 = *reinterpret_cast<const uint4*>(aHp + R64);
      vl0 = *reinterpret_cast<const uint4*>(aLp);
      vl1 = *reinterpret_cast<const uint4*>(aLp + R64);
      vb0 = *reinterpret_cast<const uint4*>(bHp);
      vb1 = *reinterpret_cast<const uint4*>(bHp + R64);
      vc0 = *reinterpret_cast<const uint4*>(bLp);
      vc1 = *reinterpret_cast<const uint4*>(bLp + R64);
    }
    bf16x8 fbh[4], fbl[4];
#pragma unroll
    for (int tj = 0; tj < 4; ++tj) {
      fbh[tj] = *reinterpret_cast<const bf16x8*>(&Bh[wc + tj * 16 + lm][q8]);
      fbl[tj] = *reinterpret_cast<const bf16x8*>(&Bl[wc + tj * 16 + lm][q8]);
    }
#pragma unroll
    for (int ti = 0; ti < 4; ++ti) {
      bf16x8 fah = *reinterpret_cast<const bf16x8*>(&Ah[wr + ti * 16 + lm][q8]);
      bf16x8 fal = *reinterpret_cast<const bf16x8*>(&Al[wr + ti * 16 + lm][q8]);
#pragma unroll
      for (int tj = 0; tj < 4; ++tj) {
        f32x4 c = acc[ti][tj];
        c = __builtin_amdgcn_mfma_f32_16x16x32_bf16(fah, fbh[tj], c, 0, 0, 0);
        c = __builtin_amdgcn_mfma_f32_16x16x32_bf16(fah, fbl[tj], c, 0, 0, 0);
        c = __builtin_amdgcn_mfma_f32_16x16x32_bf16(fal, fbh[tj], c, 0, 0, 0);
        acc[ti][tj] = c;
      }
    }
  }

  // epilogue. C/D layout: col = lane&15, row = (lane>>4)*4 + reg  [m89-verified]
  const int rq = (lane >> 4) * 4;
  const size_t rowbase = (size_t)b * 1024 + n0 + wr;

  if (EPI == 0) {
    const float* bz = dir ? c0R : c0F;
    const float* br = dir ? c1R : c1F;
    float* zb = zbuf + (size_t)dir * ((size_t)ROWS * 64);
    float* rb = rhb  + (size_t)dir * ((size_t)ROWS * 64);
    const float* hb = dir ? h1 : h0;
    if (wc == 0) {
#pragma unroll
      for (int ti = 0; ti < 4; ++ti)
#pragma unroll
        for (int tj = 0; tj < 4; ++tj) {
          const int c = tj * 16 + lm;
          const float bv = bz[c];
#pragma unroll
          for (int r = 0; r < 4; ++r) {
            const size_t row = rowbase + ti * 16 + rq + r;
            zb[row * 64 + c] = sigmoidf_(acc[ti][tj][r] + bv);
          }
        }
    } else {
#pragma unroll
      for (int ti = 0; ti < 4; ++ti)
#pragma unroll
        for (int tj = 0; tj < 4; ++tj) {
          const int c = tj * 16 + lm;
          const float bv = br[c];
#pragma unroll
          for (int r = 0; r < 4; ++r) {
            const size_t row = rowbase + ti * 16 + rq + r;
            const float rr = sigmoidf_(acc[ti][tj][r] + bv);
            rb[row * 64 + c] = rr * hb[row * 64 + c];
          }
        }
    }
  } else {
    const int dc = wc >> 6;                        // 0 or 1
    const float* bc = dc ? c0R : c0F;
    const float* zb = zbuf + (size_t)dc * ((size_t)ROWS * 64);
    float* hb = dc ? h1 : h0;
#pragma unroll
    for (int ti = 0; ti < 4; ++ti)
#pragma unroll
      for (int tj = 0; tj < 4; ++tj) {
        const int c = tj * 16 + lm;
        const float bv = bc[c];
#pragma unroll
        for (int r = 0; r < 4; ++r) {
          const size_t row = rowbase + ti * 16 + rq + r;
          const size_t idx = row * 64 + c;
          const float cc = tanhf(acc[ti][tj][r] + bv);
          const float z = zb[idx];
          const float hv = hb[idx];
          hb[idx] = z * hv + (1.0f - z) * cc;
        }
      }
  }
}

// ---------------------------------------------------------------------------
// Decoder stage 1: D1 = relu(concat(hid_f,hid_r) @ Wd1 + bd1)
// ---------------------------------------------------------------------------
__global__ __launch_bounds__(256) void dec1_kernel(
    const float* __restrict__ Hws,
    const float* __restrict__ Wd1, const float* __restrict__ bd1,
    float* __restrict__ D1)
{
  __shared__ __align__(16) float As[8][132];
  __shared__ __align__(16) float Bs[8][132];
  const int tid = threadIdx.x;
  const int row0 = blockIdx.x * 128;
  const int cb   = blockIdx.y * 128;
  const int a_nl = tid >> 1, a_k0 = (tid & 1) * 4;
  const int b_kk = tid >> 5, b_f0 = (tid & 31) * 4;
  const int tx = tid & 15, ty = tid >> 4;

  float acc[8][8] = {};
  const int arow = row0 + a_nl;
  const int l  = arow >> 14;
  const int ri = arow & 16383;

  for (int kt = 0; kt < 128; kt += 8) {
    const int k0 = kt + a_k0;
    const float* abase = (k0 < 64)
        ? (Hws + (size_t)l * HSZ + (size_t)ri * 64 + k0)
        : (Hws + (size_t)(2 + l) * HSZ + (size_t)ri * 64 + (k0 - 64));
    float4 av = *reinterpret_cast<const float4*>(abase);
    float4 bv = *reinterpret_cast<const float4*>(Wd1 + (size_t)(kt + b_kk) * 256 + cb + b_f0);
    __syncthreads();
    As[a_k0 + 0][a_nl] = av.x;
    As[a_k0 + 1][a_nl] = av.y;
    As[a_k0 + 2][a_nl] = av.z;
    As[a_k0 + 3][a_nl] = av.w;
    *reinterpret_cast<float4*>(&Bs[b_kk][b_f0]) = bv;
    __syncthreads();
#pragma unroll
    for (int kk = 0; kk < 8; ++kk) {
      const float4 a0 = *reinterpret_cast<const float4*>(&As[kk][ty * 8]);
      const float4 a1 = *reinterpret_cast<const float4*>(&As[kk][ty * 8 + 4]);
      const float4 b0 = *reinterpret_cast<const float4*>(&Bs[kk][tx * 8]);
      const float4 b1 = *reinterpret_cast<const float4*>(&Bs[kk][tx * 8 + 4]);
      const float avv[8] = {a0.x, a0.y, a0.z, a0.w, a1.x, a1.y, a1.z, a1.w};
      const float bvv[8] = {b0.x, b0.y, b0.z, b0.w, b1.x, b1.y, b1.z, b1.w};
#pragma unroll
      for (int i = 0; i < 8; ++i)
#pragma unroll
        for (int j = 0; j < 8; ++j)
          acc[i][j] = fmaf(avv[i], bvv[j], acc[i][j]);
    }
  }
#pragma unroll
  for (int i = 0; i < 8; ++i) {
    const int row = row0 + ty * 8 + i;
    float* p = D1 + (size_t)row * 256 + cb + tx * 8;
    float o[8];
#pragma unroll
    for (int j = 0; j < 8; ++j) o[j] = fmaxf(acc[i][j] + bd1[cb + tx * 8 + j], 0.0f);
    *reinterpret_cast<float4*>(p)     = make_float4(o[0], o[1], o[2], o[3]);
    *reinterpret_cast<float4*>(p + 4) = make_float4(o[4], o[5], o[6], o[7]);
  }
}

// ---------------------------------------------------------------------------
// Decoder stage 2
// ---------------------------------------------------------------------------
__global__ __launch_bounds__(256) void dec2_kernel(
    const float* __restrict__ D1, const float* __restrict__ Wd2,
    const float* __restrict__ bd2, float* __restrict__ out)
{
  __shared__ __align__(16) float As[8][132];
  __shared__ __align__(16) float Bs[8][68];
  const int tid = threadIdx.x;
  const int row0 = blockIdx.x * 128;
  const int a_nl = tid >> 1, a_k0 = (tid & 1) * 4;
  const int w_kk = tid >> 4, w_c0 = (tid & 15) * 4;
  const int tx = tid & 15, ty = tid >> 4;

  float acc[8][4] = {};
  const float* aptr = D1 + (size_t)(row0 + a_nl) * 256 + a_k0;

  for (int kt = 0; kt < 256; kt += 8) {
    float4 av = *reinterpret_cast<const float4*>(aptr + kt);
    float4 wv = make_float4(0.f, 0.f, 0.f, 0.f);
    if (tid < 128) wv = *reinterpret_cast<const float4*>(Wd2 + (size_t)(kt + w_kk) * 64 + w_c0);
    __syncthreads();
    As[a_k0 + 0][a_nl] = av.x;
    As[a_k0 + 1][a_nl] = av.y;
    As[a_k0 + 2][a_nl] = av.z;
    As[a_k0 + 3][a_nl] = av.w;
    if (tid < 128) *reinterpret_cast<float4*>(&Bs[w_kk][w_c0]) = wv;
    __syncthreads();
#pragma unroll
    for (int kk = 0; kk < 8; ++kk) {
      const float4 a0 = *reinterpret_cast<const float4*>(&As[kk][ty * 8]);
      const float4 a1 = *reinterpret_cast<const float4*>(&As[kk][ty * 8 + 4]);
      const float4 b0 = *reinterpret_cast<const float4*>(&Bs[kk][tx * 4]);
      const float avv[8] = {a0.x, a0.y, a0.z, a0.w, a1.x, a1.y, a1.z, a1.w};
      const float bvv[4] = {b0.x, b0.y, b0.z, b0.w};
#pragma unroll
      for (int i = 0; i < 8; ++i)
#pragma unroll
        for (int j = 0; j < 4; ++j)
          acc[i][j] = fmaf(avv[i], bvv[j], acc[i][j]);
    }
  }
#pragma unroll
  for (int i = 0; i < 8; ++i) {
    const int row = row0 + ty * 8 + i;
    float o[4];
#pragma unroll
    for (int j = 0; j < 4; ++j) o[j] = acc[i][j] + bd2[tx * 4 + j];
    *reinterpret_cast<float4*>(out + (size_t)row * 64 + tx * 4) = make_float4(o[0], o[1], o[2], o[3]);
  }
}

// ---------------------------------------------------------------------------
// Host driver
// ---------------------------------------------------------------------------
extern "C" void kernel_launch(void* const* d_in, const int* in_sizes, int n_in,
                              void* d_out, int out_size, void* d_ws, size_t ws_size,
                              hipStream_t stream)
{
  (void)in_sizes; (void)n_in; (void)out_size; (void)ws_size;
  const float* inputs = (const float*)d_in[0];
  const float* mask   = (const float*)d_in[1];
  const float* adj    = (const float*)d_in[2];
  const float* Wp1    = (const float*)d_in[3];
  const float* bp1    = (const float*)d_in[4];
  const float* Wp2    = (const float*)d_in[5];
  const float* bp2    = (const float*)d_in[6];
  const float* Wz_f   = (const float*)d_in[7];
  const float* Wr_f   = (const float*)d_in[8];
  const float* Wc_f   = (const float*)d_in[9];
  const float* bz_f   = (const float*)d_in[10];
  const float* br_f   = (const float*)d_in[11];
  const float* bc_f   = (const float*)d_in[12];
  const float* Wz_r   = (const float*)d_in[13];
  const float* Wr_r   = (const float*)d_in[14];
  const float* Wc_r   = (const float*)d_in[15];
  const float* bz_r   = (const float*)d_in[16];
  const float* br_r   = (const float*)d_in[17];
  const float* bc_r   = (const float*)d_in[18];
  const float* Wd1    = (const float*)d_in[19];
  const float* bd1    = (const float*)d_in[20];
  const float* Wd2    = (const float*)d_in[21];
  const float* bd2    = (const float*)d_in[22];

  float* ws = (float*)d_ws;
  float* S0 = ws;                                   // TOT
  float* X  = S0 + TOT;                             // TOT*64
  float* H  = X + (size_t)TOT * 64;                 // 4*HSZ [dir*2+l]
  float* Z  = H + 4 * HSZ;                          // 2*HSZ
  float* RH = Z + 2 * HSZ;                          // 2*HSZ
  ushort_t* ADJH = (ushort_t*)(RH + 2 * HSZ);       // 1M
  ushort_t* ADJL = ADJH + (size_t)1024 * 1024;      // 1M
  float* U = (float*)(ADJL + (size_t)1024 * 1024);  // union region
  ushort_t* G1TH = (ushort_t*)U;                    // 2*16*128*1024
  ushort_t* G1TL = G1TH + (size_t)2 * 16 * 128 * 1024;
  ushort_t* G2TH = G1TL + (size_t)2 * 16 * 128 * 1024;
  ushort_t* G2TL = G2TH + (size_t)16 * 128 * 1024;
  float* D1 = U;                                    // aliases G buffers (after loop)

  hipMemsetAsync(H, 0, 4 * HSZ * sizeof(float), stream);

  seq_kernel<<<dim3((HALF + 255) / 256), 256, 0, stream>>>(inputs, S0);
  proj_kernel<<<dim3(TOT / 128), 256, 0, stream>>>(S0, mask, Wp1, bp1, Wp2, bp2, X);
  adjsplit_kernel<<<dim3(4096), 256, 0, stream>>>(adj, ADJH, ADJL);

  for (int t = 0; t < Tn; ++t) {
    for (int l = 0; l < Ln; ++l) {
      const float* x0 = (l == 0) ? (X + (size_t)t * HSZ) : H;
      const float* x1 = (l == 0) ? (X + (size_t)(Tn - 1 - t) * HSZ) : (H + 2 * HSZ);
      float* h0 = H + (size_t)l * HSZ;
      float* h1 = H + (size_t)(2 + l) * HSZ;

      prez_kernel<<<dim3(256, 1, 2), 256, 0, stream>>>(
          x0, x1, h0, h1,
          Wz_f + l * 8192, Wz_r + l * 8192, Wr_f + l * 8192, Wr_r + l * 8192,
          G1TH, G1TL);
      conv_mfma<0><<<dim3(8, 16, 2), 256, 0, stream>>>(
          ADJH, ADJL, G1TH, G1TL,
          bz_f + l * 64, bz_r + l * 64, br_f + l * 64, br_r + l * 64,
          Z, RH, h0, h1);
      prec_kernel<<<dim3(256, 1, 2), 256, 0, stream>>>(
          x0, x1, RH, Wc_f + l * 8192, Wc_r + l * 8192, G2TH, G2TL);
      conv_mfma<1><<<dim3(8, 16, 1), 256, 0, stream>>>(
          ADJH, ADJL, G2TH, G2TL,
          bc_f + l * 64, bc_r + l * 64, bc_f + l * 64, bc_r + l * 64,
          Z, RH, h0, h1);
    }
  }

  dec1_kernel<<<dim3(256, 2), 256, 0, stream>>>(H, Wd1, bd1, D1);
  dec2_kernel<<<dim3(256, 1), 256, 0, stream>>>(D1, Wd2, bd2, (float*)d_out);
}

// Round 4
// 3413.247 us; speedup vs baseline: 2.5579x; 1.0952x over previous
//
#include <hip/hip_runtime.h>
#include <cstdint>
#include <cstddef>

constexpr int Tn = 12, Bn = 16, Nn = 1024, Hn = 64, Ln = 2;
constexpr int ROWS = Bn * Nn;                 // 16384
constexpr int TOT  = Tn * Bn * Nn;            // 196608
constexpr int HALF = TOT / 2;
constexpr size_t HSZ = (size_t)Bn * Nn * Hn;  // 1048576 floats

#define DEVFN __device__ __forceinline__

typedef __attribute__((ext_vector_type(4))) float f32x4;
typedef __attribute__((ext_vector_type(8))) __bf16 bf16x8;
typedef unsigned short ushort_t;

// weight-plane offsets (in elements) inside WH/WL
constexpr size_t WOFF_PZ = 0;        // [d][l][n:128][k:128]  prez B
constexpr size_t WOFF_PC = 65536;    // [d][l][n:64][k:128]   prec B
constexpr size_t WOFF_P2 = 98304;    // [n:64][k:256]         proj B (Wp2)
constexpr size_t WOFF_D1 = 114688;   // [n:256][k:128]        dec1 B (Wd1)
constexpr size_t WOFF_D2 = 147456;   // [n:64][k:256]         dec2 B (Wd2)
constexpr size_t WTOT    = 163840;

// ---------------------------------------------------------------------------
// bf16 split helpers (RNE)
// ---------------------------------------------------------------------------
DEVFN ushort_t f2bf_rne(float f) {
  uint32_t u = __float_as_uint(f);
  uint32_t r = u + 0x7FFFu + ((u >> 16) & 1u);
  return (ushort_t)(r >> 16);
}
DEVFN float bf2f(ushort_t h) { return __uint_as_float(((uint32_t)h) << 16); }

DEVFN void split8(const float* f, bf16x8& h8, bf16x8& l8) {
  alignas(16) ushort_t hs[8], ls[8];
#pragma unroll
  for (int j = 0; j < 8; ++j) {
    ushort_t h = f2bf_rne(f[j]);
    hs[j] = h;
    ls[j] = f2bf_rne(f[j] - bf2f(h));
  }
  h8 = *reinterpret_cast<bf16x8*>(hs);
  l8 = *reinterpret_cast<bf16x8*>(ls);
}

DEVFN f32x4 mm3(bf16x8 ah, bf16x8 al, bf16x8 bh, bf16x8 bl, f32x4 c) {
  c = __builtin_amdgcn_mfma_f32_16x16x32_bf16(ah, bh, c, 0, 0, 0);
  c = __builtin_amdgcn_mfma_f32_16x16x32_bf16(ah, bl, c, 0, 0, 0);
  c = __builtin_amdgcn_mfma_f32_16x16x32_bf16(al, bh, c, 0, 0, 0);
  return c;
}

DEVFN bf16x8 ld16(const ushort_t* p) { return *reinterpret_cast<const bf16x8*>(p); }

DEVFN void ld8f(const float* p, float* out) {
  float4 v0 = *reinterpret_cast<const float4*>(p);
  float4 v1 = *reinterpret_cast<const float4*>(p + 4);
  out[0] = v0.x; out[1] = v0.y; out[2] = v0.z; out[3] = v0.w;
  out[4] = v1.x; out[5] = v1.y; out[6] = v1.z; out[7] = v1.w;
}

// ---------------------------------------------------------------------------
// threefry2x32 (key 0,42) + XLA-exact normal
// ---------------------------------------------------------------------------
DEVFN uint32_t rotl32(uint32_t v, int d) { return (v << d) | (v >> (32 - d)); }

DEVFN void threefry_0_42(uint32_t& x0, uint32_t& x1) {
  const uint32_t k0 = 0u, k1 = 42u, k2 = k0 ^ k1 ^ 0x1BD11BDAu;
  x0 += k0; x1 += k1;
#define TFR(r) { x0 += x1; x1 = rotl32(x1, r); x1 ^= x0; }
  TFR(13) TFR(15) TFR(26) TFR(6)
  x0 += k1; x1 += k2 + 1u;
  TFR(17) TFR(29) TFR(16) TFR(24)
  x0 += k2; x1 += k0 + 2u;
  TFR(13) TFR(15) TFR(26) TFR(6)
  x0 += k0; x1 += k1 + 3u;
  TFR(17) TFR(29) TFR(16) TFR(24)
  x0 += k1; x1 += k2 + 4u;
  TFR(13) TFR(15) TFR(26) TFR(6)
  x0 += k2; x1 += k0 + 5u;
#undef TFR
}

DEVFN float erfinv32(float x) {
  float w = -log1pf(-x * x);
  float p;
  if (w < 5.0f) {
    w = w - 2.5f;
    p = 2.81022636e-08f;
    p = fmaf(p, w, 3.43273939e-07f);
    p = fmaf(p, w, -3.5233877e-06f);
    p = fmaf(p, w, -4.39150654e-06f);
    p = fmaf(p, w, 0.00021858087f);
    p = fmaf(p, w, -0.00125372503f);
    p = fmaf(p, w, -0.00417768164f);
    p = fmaf(p, w, 0.246640727f);
    p = fmaf(p, w, 1.50140941f);
  } else {
    w = sqrtf(w) - 3.0f;
    p = -0.000200214257f;
    p = fmaf(p, w, 0.000100950558f);
    p = fmaf(p, w, 0.00134934322f);
    p = fmaf(p, w, -0.00367342844f);
    p = fmaf(p, w, 0.00573950773f);
    p = fmaf(p, w, -0.0076224613f);
    p = fmaf(p, w, 0.00943887047f);
    p = fmaf(p, w, 1.00167406f);
    p = fmaf(p, w, 2.83297682f);
  }
  return p * x;
}

DEVFN float bits_to_normal(uint32_t bits) {
  float f = __uint_as_float((bits >> 9) | 0x3f800000u) - 1.0f;
  const float lo = -0.99999994f;
  float u = fmaf(f, 2.0f, lo);
  u = fmaxf(lo, u);
  return 1.41421356237f * erfinv32(u);
}

__global__ __launch_bounds__(256) void seq_kernel(const float* __restrict__ inputs,
                                                  float* __restrict__ s0) {
  int i = blockIdx.x * 256 + threadIdx.x;
  if (i >= HALF) return;
  uint32_t x0 = (uint32_t)i, x1 = (uint32_t)(i + HALF);
  threefry_0_42(x0, x1);
  s0[i]        = inputs[i]        + 0.01f * bits_to_normal(x0);
  s0[i + HALF] = inputs[i + HALF] + 0.01f * bits_to_normal(x1);
}

DEVFN float sigmoidf_(float x) { return 1.0f / (1.0f + expf(-x)); }

// ---------------------------------------------------------------------------
// adj -> bf16 hi/lo planes
// ---------------------------------------------------------------------------
__global__ __launch_bounds__(256) void adjsplit_kernel(const float* __restrict__ adj,
                                                       ushort_t* __restrict__ hi,
                                                       ushort_t* __restrict__ lo) {
  int i = blockIdx.x * 256 + threadIdx.x;
  float v = adj[i];
  ushort_t h = f2bf_rne(v);
  hi[i] = h;
  lo[i] = f2bf_rne(v - bf2f(h));
}

// ---------------------------------------------------------------------------
// wprep: split + transpose all GEMM B-weights into [n][k] bf16 hi/lo planes
// ---------------------------------------------------------------------------
__global__ __launch_bounds__(256) void wprep_kernel(
    const float* __restrict__ WzF, const float* __restrict__ WrF, const float* __restrict__ WcF,
    const float* __restrict__ WzR, const float* __restrict__ WrR, const float* __restrict__ WcR,
    const float* __restrict__ Wp2, const float* __restrict__ Wd1, const float* __restrict__ Wd2,
    ushort_t* __restrict__ WH, ushort_t* __restrict__ WL)
{
  size_t i = (size_t)blockIdx.x * 256 + threadIdx.x;
  if (i >= WTOT) return;
  float v;
  if (i < WOFF_PC) {                          // PZ [d][l][n:128][k:128]
    int d = (i >> 15) & 1, l = (i >> 14) & 1, n = (i >> 7) & 127, k = i & 127;
    const float* W = (n < 64) ? (d ? WzR : WzF) : (d ? WrR : WrF);
    v = W[l * 8192 + k * 64 + (n & 63)];
  } else if (i < WOFF_P2) {                   // PC [d][l][n:64][k:128]
    size_t j = i - WOFF_PC;
    int d = (j >> 14) & 1, l = (j >> 13) & 1, n = (j >> 7) & 63, k = j & 127;
    const float* W = d ? WcR : WcF;
    v = W[l * 8192 + k * 64 + n];
  } else if (i < WOFF_D1) {                   // P2 [n:64][k:256]
    size_t j = i - WOFF_P2;
    int n = j >> 8, k = j & 255;
    v = Wp2[k * 64 + n];
  } else if (i < WOFF_D2) {                   // D1 [n:256][k:128]
    size_t j = i - WOFF_D1;
    int n = j >> 7, k = j & 127;
    v = Wd1[k * 256 + n];
  } else {                                    // D2 [n:64][k:256]
    size_t j = i - WOFF_D2;
    int n = j >> 8, k = j & 255;
    v = Wd2[k * 64 + n];
  }
  ushort_t h = f2bf_rne(v);
  WH[i] = h;
  WL[i] = f2bf_rne(v - bf2f(h));
}

// ---------------------------------------------------------------------------
// proj: X[m][64] = relu(s0*W0+s1*W1+bp1) @ Wp2 + bp2   (M=196608,N=64,K=256)
// MFMA, A generated in registers, B from pre-split planes. Block 256 rows.
// ---------------------------------------------------------------------------
__global__ __launch_bounds__(256) void proj_mfma(
    const float* __restrict__ s0g, const float* __restrict__ s1g,
    const float* __restrict__ Wp1, const float* __restrict__ bp1,
    const float* __restrict__ bp2,
    const ushort_t* __restrict__ WH, const ushort_t* __restrict__ WL,
    float* __restrict__ X)
{
  __shared__ float W0[256], W1[256], Bb[256], SS0[256], SS1[256];
  const int tid = threadIdx.x;
  const int row0 = blockIdx.x * 256;
  W0[tid] = Wp1[tid];
  W1[tid] = Wp1[256 + tid];
  Bb[tid] = bp1[tid];
  SS0[tid] = s0g[row0 + tid];
  SS1[tid] = s1g[row0 + tid];
  __syncthreads();

  const int lane = tid & 63, wave = tid >> 6;
  const int lm = lane & 15, q8 = (lane >> 4) * 8;
  const ushort_t* P2H = WH + WOFF_P2;
  const ushort_t* P2L = WL + WOFF_P2;

  float sv0[4], sv1[4];
#pragma unroll
  for (int ti = 0; ti < 4; ++ti) {
    sv0[ti] = SS0[wave * 64 + ti * 16 + lm];
    sv1[ti] = SS1[wave * 64 + ti * 16 + lm];
  }

  f32x4 acc[4][4];
#pragma unroll
  for (int i = 0; i < 4; ++i)
#pragma unroll
    for (int j = 0; j < 4; ++j) acc[i][j] = (f32x4)0.0f;

  for (int kt = 0; kt < 8; ++kt) {
    const int kc = kt * 32 + q8;
    bf16x8 bh[4], bl[4];
#pragma unroll
    for (int tj = 0; tj < 4; ++tj) {
      bh[tj] = ld16(P2H + (size_t)(tj * 16 + lm) * 256 + kc);
      bl[tj] = ld16(P2L + (size_t)(tj * 16 + lm) * 256 + kc);
    }
    float w08[8], w18[8], bb8[8];
#pragma unroll
    for (int j = 0; j < 8; ++j) { w08[j] = W0[kc + j]; w18[j] = W1[kc + j]; bb8[j] = Bb[kc + j]; }
#pragma unroll
    for (int ti = 0; ti < 4; ++ti) {
      float a8[8];
#pragma unroll
      for (int j = 0; j < 8; ++j)
        a8[j] = fmaxf(fmaf(sv0[ti], w08[j], fmaf(sv1[ti], w18[j], bb8[j])), 0.0f);
      bf16x8 ah, al;
      split8(a8, ah, al);
#pragma unroll
      for (int tj = 0; tj < 4; ++tj) acc[ti][tj] = mm3(ah, al, bh[tj], bl[tj], acc[ti][tj]);
    }
  }

  const int rq = (lane >> 4) * 4;
  const int rowbase = row0 + wave * 64;
#pragma unroll
  for (int ti = 0; ti < 4; ++ti)
#pragma unroll
    for (int tj = 0; tj < 4; ++tj) {
      const int col = tj * 16 + lm;
      const float bv = bp2[col];
#pragma unroll
      for (int r = 0; r < 4; ++r)
        X[(size_t)(rowbase + ti * 16 + rq + r) * 64 + col] = acc[ti][tj][r] + bv;
    }
}

// ---------------------------------------------------------------------------
// prez: G1t[dir][b][c:128][m:1024] (bf16 hi/lo) = transpose([x|h] @ [Wz|Wr])
// MFMA core (A direct from global fp32, split in regs), LDS-transpose epilogue.
// Block: 256 thr, tile 128 rows x 128 cols, K=128. Grid (128,1,2).
// ---------------------------------------------------------------------------
__global__ __launch_bounds__(256) void prez_mfma(
    const float* __restrict__ x0p, const float* __restrict__ x1p,
    const float* __restrict__ h0p, const float* __restrict__ h1p,
    const ushort_t* __restrict__ WH, const ushort_t* __restrict__ WL,
    int l,
    ushort_t* __restrict__ G1tH, ushort_t* __restrict__ G1tL)
{
  __shared__ float T[128][132];
  const int tid = threadIdx.x;
  const int row0 = blockIdx.x * 128;
  const int dir  = blockIdx.z;
  const int b    = row0 >> 10;
  const int nloc = row0 & 1023;
  const float* __restrict__ xs = dir ? x1p : x0p;
  const float* __restrict__ hs = dir ? h1p : h0p;
  const ushort_t* BH = WH + WOFF_PZ + (size_t)(dir * 2 + l) * 16384;
  const ushort_t* BL = WL + WOFF_PZ + (size_t)(dir * 2 + l) * 16384;

  const int lane = tid & 63, wave = tid >> 6;
  const int wr = (wave >> 1) * 64, wc = (wave & 1) * 64;
  const int lm = lane & 15, q8 = (lane >> 4) * 8;

  f32x4 acc[4][4];
#pragma unroll
  for (int i = 0; i < 4; ++i)
#pragma unroll
    for (int j = 0; j < 4; ++j) acc[i][j] = (f32x4)0.0f;

#pragma unroll
  for (int kt = 0; kt < 4; ++kt) {
    const int k0 = kt * 32 + q8;
    bf16x8 bh[4], bl[4];
#pragma unroll
    for (int tj = 0; tj < 4; ++tj) {
      const size_t off = (size_t)(wc + tj * 16 + lm) * 128 + k0;
      bh[tj] = ld16(BH + off);
      bl[tj] = ld16(BL + off);
    }
#pragma unroll
    for (int ti = 0; ti < 4; ++ti) {
      const int row = row0 + wr + ti * 16 + lm;
      const float* src = (k0 < 64) ? (xs + (size_t)row * 64 + k0)
                                   : (hs + (size_t)row * 64 + (k0 - 64));
      float a8[8];
      ld8f(src, a8);
      bf16x8 ah, al;
      split8(a8, ah, al);
#pragma unroll
      for (int tj = 0; tj < 4; ++tj) acc[ti][tj] = mm3(ah, al, bh[tj], bl[tj], acc[ti][tj]);
    }
  }

  const int rq = (lane >> 4) * 4;
#pragma unroll
  for (int ti = 0; ti < 4; ++ti)
#pragma unroll
    for (int tj = 0; tj < 4; ++tj)
#pragma unroll
      for (int r = 0; r < 4; ++r)
        T[wc + tj * 16 + lm][wr + ti * 16 + rq + r] = acc[ti][tj][r];
  __syncthreads();

  {
    const int c = tid >> 1, mc = (tid & 1) * 64;
    const size_t base = ((size_t)(dir * 16 + b) * 128 + c) * 1024 + nloc + mc;
#pragma unroll
    for (int q = 0; q < 4; ++q) {
      alignas(16) ushort_t hsv[16], lsv[16];
#pragma unroll
      for (int k = 0; k < 16; ++k) {
        float v = T[c][mc + q * 16 + k];
        ushort_t h = f2bf_rne(v);
        hsv[k] = h;
        lsv[k] = f2bf_rne(v - bf2f(h));
      }
      *reinterpret_cast<uint4*>(G1tH + base + q * 16)     = *reinterpret_cast<uint4*>(&hsv[0]);
      *reinterpret_cast<uint4*>(G1tH + base + q * 16 + 8) = *reinterpret_cast<uint4*>(&hsv[8]);
      *reinterpret_cast<uint4*>(G1tL + base + q * 16)     = *reinterpret_cast<uint4*>(&lsv[0]);
      *reinterpret_cast<uint4*>(G1tL + base + q * 16 + 8) = *reinterpret_cast<uint4*>(&lsv[8]);
    }
  }
}

// ---------------------------------------------------------------------------
// prec: G2t[b][dir*64+c][m:1024] (bf16 hi/lo) = transpose([x|r*h] @ Wc)
// Block: 128 thr, tile 128 rows x 64 cols, K=128. Grid (128,1,2).
// ---------------------------------------------------------------------------
__global__ __launch_bounds__(128) void prec_mfma(
    const float* __restrict__ x0p, const float* __restrict__ x1p,
    const float* __restrict__ rhbuf,
    const ushort_t* __restrict__ WH, const ushort_t* __restrict__ WL,
    int l,
    ushort_t* __restrict__ G2tH, ushort_t* __restrict__ G2tL)
{
  __shared__ float T[64][132];
  const int tid = threadIdx.x;
  const int row0 = blockIdx.x * 128;
  const int dir  = blockIdx.z;
  const int b    = row0 >> 10;
  const int nloc = row0 & 1023;
  const float* __restrict__ xs = dir ? x1p : x0p;
  const float* __restrict__ rs = rhbuf + (size_t)dir * ((size_t)ROWS * 64);
  const ushort_t* BH = WH + WOFF_PC + (size_t)(dir * 2 + l) * 8192;
  const ushort_t* BL = WL + WOFF_PC + (size_t)(dir * 2 + l) * 8192;

  const int lane = tid & 63, wave = tid >> 6;   // wave 0..1
  const int wr = wave * 64;
  const int lm = lane & 15, q8 = (lane >> 4) * 8;

  f32x4 acc[4][4];
#pragma unroll
  for (int i = 0; i < 4; ++i)
#pragma unroll
    for (int j = 0; j < 4; ++j) acc[i][j] = (f32x4)0.0f;

#pragma unroll
  for (int kt = 0; kt < 4; ++kt) {
    const int k0 = kt * 32 + q8;
    bf16x8 bh[4], bl[4];
#pragma unroll
    for (int tj = 0; tj < 4; ++tj) {
      const size_t off = (size_t)(tj * 16 + lm) * 128 + k0;
      bh[tj] = ld16(BH + off);
      bl[tj] = ld16(BL + off);
    }
#pragma unroll
    for (int ti = 0; ti < 4; ++ti) {
      const int row = row0 + wr + ti * 16 + lm;
      const float* src = (k0 < 64) ? (xs + (size_t)row * 64 + k0)
                                   : (rs + (size_t)row * 64 + (k0 - 64));
      float a8[8];
      ld8f(src, a8);
      bf16x8 ah, al;
      split8(a8, ah, al);
#pragma unroll
      for (int tj = 0; tj < 4; ++tj) acc[ti][tj] = mm3(ah, al, bh[tj], bl[tj], acc[ti][tj]);
    }
  }

  const int rq = (lane >> 4) * 4;
#pragma unroll
  for (int ti = 0; ti < 4; ++ti)
#pragma unroll
    for (int tj = 0; tj < 4; ++tj)
#pragma unroll
      for (int r = 0; r < 4; ++r)
        T[tj * 16 + lm][wr + ti * 16 + rq + r] = acc[ti][tj][r];
  __syncthreads();

  {
    const int c = tid >> 1, mc = (tid & 1) * 64;
    const size_t base = ((size_t)b * 128 + (size_t)dir * 64 + c) * 1024 + nloc + mc;
#pragma unroll
    for (int q = 0; q < 4; ++q) {
      alignas(16) ushort_t hsv[16], lsv[16];
#pragma unroll
      for (int k = 0; k < 16; ++k) {
        float v = T[c][mc + q * 16 + k];
        ushort_t h = f2bf_rne(v);
        hsv[k] = h;
        lsv[k] = f2bf_rne(v - bf2f(h));
      }
      *reinterpret_cast<uint4*>(G2tH + base + q * 16)     = *reinterpret_cast<uint4*>(&hsv[0]);
      *reinterpret_cast<uint4*>(G2tH + base + q * 16 + 8) = *reinterpret_cast<uint4*>(&hsv[8]);
      *reinterpret_cast<uint4*>(G2tL + base + q * 16)     = *reinterpret_cast<uint4*>(&lsv[0]);
      *reinterpret_cast<uint4*>(G2tL + base + q * 16 + 8) = *reinterpret_cast<uint4*>(&lsv[8]);
    }
  }
}

// ---------------------------------------------------------------------------
// conv_mfma (unchanged from R3 — verified)
// ---------------------------------------------------------------------------
template<int EPI>
__global__ __launch_bounds__(256) void conv_mfma(
    const ushort_t* __restrict__ adjHi, const ushort_t* __restrict__ adjLo,
    const ushort_t* __restrict__ BtH,  const ushort_t* __restrict__ BtL,
    const float* __restrict__ c0F, const float* __restrict__ c0R,
    const float* __restrict__ c1F, const float* __restrict__ c1R,
    float* __restrict__ zbuf, float* __restrict__ rhb,
    float* __restrict__ h0, float* __restrict__ h1)
{
  __shared__ ushort_t Ah[128][40], Al[128][40], Bh[128][40], Bl[128][40];
  const int tid = threadIdx.x;
  const int n0  = blockIdx.x * 128;
  const int b   = blockIdx.y;
  const int dir = blockIdx.z;

  const size_t boff = (EPI == 0) ? ((size_t)(dir * 16 + b) * 128) * 1024
                                 : ((size_t)b * 128) * 1024;

  const int r0 = tid >> 2, ch = tid & 3;
  const ushort_t* aHp = adjHi + (size_t)(n0 + r0) * 1024 + ch * 8;
  const ushort_t* aLp = adjLo + (size_t)(n0 + r0) * 1024 + ch * 8;
  const ushort_t* bHp = BtH + boff + (size_t)r0 * 1024 + ch * 8;
  const ushort_t* bLp = BtL + boff + (size_t)r0 * 1024 + ch * 8;
  const size_t R64 = (size_t)64 * 1024;

  f32x4 acc[4][4];
#pragma unroll
  for (int i = 0; i < 4; ++i)
#pragma unroll
    for (int j = 0; j < 4; ++j) acc[i][j] = (f32x4)0.0f;

  const int lane = tid & 63, wave = tid >> 6;
  const int wr = (wave >> 1) * 64, wc = (wave & 1) * 64;
  const int lm = lane & 15, q8 = (lane >> 4) * 8;

  uint4 va0 = *reinterpret_cast<const uint4*>(aHp);
  uint4 va1 = *reinterpret_cast<const uint4*>(aHp + R64);
  uint4 vl0 = *reinterpret_cast<const uint4*>(aLp);
  uint4 vl1 = *reinterpret_cast<const uint4*>(aLp + R64);
  uint4 vb0 = *reinterpret_cast<const uint4*>(bHp);
  uint4 vb1 = *reinterpret_cast<const uint4*>(bHp + R64);
  uint4 vc0 = *reinterpret_cast<const uint4*>(bLp);
  uint4 vc1 = *reinterpret_cast<const uint4*>(bLp + R64);

  for (int kt = 0; kt < 32; ++kt) {
    __syncthreads();
    *reinterpret_cast<uint4*>(&Ah[r0][ch * 8])      = va0;
    *reinterpret_cast<uint4*>(&Ah[r0 + 64][ch * 8]) = va1;
    *reinterpret_cast<uint4*>(&Al[r0][ch * 8])      = vl0;
    *reinterpret_cast<uint4*>(&Al[r0 + 64][ch * 8]) = vl1;
    *reinterpret_cast<uint4*>(&Bh[r0][ch * 8])      = vb0;
    *reinterpret_cast<uint4*>(&Bh[r0 + 64][ch * 8]) = vb1;
    *reinterpret_cast<uint4*>(&Bl[r0][ch * 8])      = vc0;
    *reinterpret_cast<uint4*>(&Bl[r0 + 64][ch * 8]) = vc1;
    __syncthreads();
    if (kt < 31) {
      aHp += 32; aLp += 32; bHp += 32; bLp += 32;
      va0 = *reinterpret_cast<const uint4*>(aHp);
      va1 = *reinterpret_cast<const uint4*>(aHp + R64);
      vl0 = *reinterpret_cast<const uint4*>(aLp);
      vl1 = *reinterpret_cast<const uint4*>(aLp + R64);
      vb0 = *reinterpret_cast<const uint4*>(bHp);
      vb1 = *reinterpret_cast<const uint4*>(bHp + R64);
      vc0 = *reinterpret_cast<const uint4*>(bLp);
      vc1 = *reinterpret_cast<const uint4*>(bLp + R64);
    }
    bf16x8 fbh[4], fbl[4];
#pragma unroll
    for (int tj = 0; tj < 4; ++tj) {
      fbh[tj] = *reinterpret_cast<const bf16x8*>(&Bh[wc + tj * 16 + lm][q8]);
      fbl[tj] = *reinterpret_cast<const bf16x8*>(&Bl[wc + tj * 16 + lm][q8]);
    }
#pragma unroll
    for (int ti = 0; ti < 4; ++ti) {
      bf16x8 fah = *reinterpret_cast<const bf16x8*>(&Ah[wr + ti * 16 + lm][q8]);
      bf16x8 fal = *reinterpret_cast<const bf16x8*>(&Al[wr + ti * 16 + lm][q8]);
#pragma unroll
      for (int tj = 0; tj < 4; ++tj) {
        f32x4 c = acc[ti][tj];
        c = __builtin_amdgcn_mfma_f32_16x16x32_bf16(fah, fbh[tj], c, 0, 0, 0);
        c = __builtin_amdgcn_mfma_f32_16x16x32_bf16(fah, fbl[tj], c, 0, 0, 0);
        c = __builtin_amdgcn_mfma_f32_16x16x32_bf16(fal, fbh[tj], c, 0, 0, 0);
        acc[ti][tj] = c;
      }
    }
  }

  const int rq = (lane >> 4) * 4;
  const size_t rowbase = (size_t)b * 1024 + n0 + wr;

  if (EPI == 0) {
    const float* bz = dir ? c0R : c0F;
    const float* br = dir ? c1R : c1F;
    float* zb = zbuf + (size_t)dir * ((size_t)ROWS * 64);
    float* rb = rhb  + (size_t)dir * ((size_t)ROWS * 64);
    const float* hb = dir ? h1 : h0;
    if (wc == 0) {
#pragma unroll
      for (int ti = 0; ti < 4; ++ti)
#pragma unroll
        for (int tj = 0; tj < 4; ++tj) {
          const int c = tj * 16 + lm;
          const float bv = bz[c];
#pragma unroll
          for (int r = 0; r < 4; ++r) {
            const size_t row = rowbase + ti * 16 + rq + r;
            zb[row * 64 + c] = sigmoidf_(acc[ti][tj][r] + bv);
          }
        }
    } else {
#pragma unroll
      for (int ti = 0; ti < 4; ++ti)
#pragma unroll
        for (int tj = 0; tj < 4; ++tj) {
          const int c = tj * 16 + lm;
          const float bv = br[c];
#pragma unroll
          for (int r = 0; r < 4; ++r) {
            const size_t row = rowbase + ti * 16 + rq + r;
            const float rr = sigmoidf_(acc[ti][tj][r] + bv);
            rb[row * 64 + c] = rr * hb[row * 64 + c];
          }
        }
    }
  } else {
    const int dc = wc >> 6;
    const float* bc = dc ? c0R : c0F;
    const float* zb = zbuf + (size_t)dc * ((size_t)ROWS * 64);
    float* hb = dc ? h1 : h0;
#pragma unroll
    for (int ti = 0; ti < 4; ++ti)
#pragma unroll
      for (int tj = 0; tj < 4; ++tj) {
        const int c = tj * 16 + lm;
        const float bv = bc[c];
#pragma unroll
        for (int r = 0; r < 4; ++r) {
          const size_t row = rowbase + ti * 16 + rq + r;
          const size_t idx = row * 64 + c;
          const float cc = tanhf(acc[ti][tj][r] + bv);
          const float z = zb[idx];
          const float hv = hb[idx];
          hb[idx] = z * hv + (1.0f - z) * cc;
        }
      }
  }
}

// ---------------------------------------------------------------------------
// dec1: D1[row][256] = relu(concat(hid_f,hid_r)[row] @ Wd1 + bd1)
// MFMA; block 128 rows x 128 cols (cb half). Grid (256,2).
// ---------------------------------------------------------------------------
__global__ __launch_bounds__(256) void dec1_mfma(
    const float* __restrict__ Hws,
    const ushort_t* __restrict__ WH, const ushort_t* __restrict__ WL,
    const float* __restrict__ bd1,
    float* __restrict__ D1)
{
  const int tid = threadIdx.x;
  const int row0 = blockIdx.x * 128;
  const int cb   = blockIdx.y * 128;
  const int l  = row0 >> 14;
  const int ri0 = row0 & 16383;
  const float* Hf = Hws + (size_t)l * HSZ;
  const float* Hr = Hws + (size_t)(2 + l) * HSZ;
  const ushort_t* BH = WH + WOFF_D1;
  const ushort_t* BL = WL + WOFF_D1;

  const int lane = tid & 63, wave = tid >> 6;
  const int wr = (wave >> 1) * 64, wc = (wave & 1) * 64;
  const int lm = lane & 15, q8 = (lane >> 4) * 8;

  f32x4 acc[4][4];
#pragma unroll
  for (int i = 0; i < 4; ++i)
#pragma unroll
    for (int j = 0; j < 4; ++j) acc[i][j] = (f32x4)0.0f;

#pragma unroll
  for (int kt = 0; kt < 4; ++kt) {
    const int k0 = kt * 32 + q8;
    bf16x8 bh[4], bl[4];
#pragma unroll
    for (int tj = 0; tj < 4; ++tj) {
      const size_t off = (size_t)(cb + wc + tj * 16 + lm) * 128 + k0;
      bh[tj] = ld16(BH + off);
      bl[tj] = ld16(BL + off);
    }
#pragma unroll
    for (int ti = 0; ti < 4; ++ti) {
      const int ri = ri0 + wr + ti * 16 + lm;
      const float* src = (k0 < 64) ? (Hf + (size_t)ri * 64 + k0)
                                   : (Hr + (size_t)ri * 64 + (k0 - 64));
      float a8[8];
      ld8f(src, a8);
      bf16x8 ah, al;
      split8(a8, ah, al);
#pragma unroll
      for (int tj = 0; tj < 4; ++tj) acc[ti][tj] = mm3(ah, al, bh[tj], bl[tj], acc[ti][tj]);
    }
  }

  const int rq = (lane >> 4) * 4;
#pragma unroll
  for (int ti = 0; ti < 4; ++ti)
#pragma unroll
    for (int tj = 0; tj < 4; ++tj) {
      const int col = cb + wc + tj * 16 + lm;
      const float bv = bd1[col];
#pragma unroll
      for (int r = 0; r < 4; ++r) {
        const size_t row = row0 + wr + ti * 16 + rq + r;
        D1[row * 256 + col] = fmaxf(acc[ti][tj][r] + bv, 0.0f);
      }
    }
}

// ---------------------------------------------------------------------------
// dec2: out[row][64] = D1[row] @ Wd2 + bd2.  Block 256 rows. Grid 128.
// ---------------------------------------------------------------------------
__global__ __launch_bounds__(256) void dec2_mfma(
    const float* __restrict__ D1,
    const ushort_t* __restrict__ WH, const ushort_t* __restrict__ WL,
    const float* __restrict__ bd2,
    float* __restrict__ out)
{
  const int tid = threadIdx.x;
  const int row0 = blockIdx.x * 256;
  const ushort_t* BH = WH + WOFF_D2;
  const ushort_t* BL = WL + WOFF_D2;

  const int lane = tid & 63, wave = tid >> 6;
  const int wr = wave * 64;
  const int lm = lane & 15, q8 = (lane >> 4) * 8;

  f32x4 acc[4][4];
#pragma unroll
  for (int i = 0; i < 4; ++i)
#pragma unroll
    for (int j = 0; j < 4; ++j) acc[i][j] = (f32x4)0.0f;

#pragma unroll
  for (int kt = 0; kt < 8; ++kt) {
    const int k0 = kt * 32 + q8;
    bf16x8 bh[4], bl[4];
#pragma unroll
    for (int tj = 0; tj < 4; ++tj) {
      const size_t off = (size_t)(tj * 16 + lm) * 256 + k0;
      bh[tj] = ld16(BH + off);
      bl[tj] = ld16(BL + off);
    }
#pragma unroll
    for (int ti = 0; ti < 4; ++ti) {
      const size_t row = row0 + wr + ti * 16 + lm;
      float a8[8];
      ld8f(D1 + row * 256 + k0, a8);
      bf16x8 ah, al;
      split8(a8, ah, al);
#pragma unroll
      for (int tj = 0; tj < 4; ++tj) acc[ti][tj] = mm3(ah, al, bh[tj], bl[tj], acc[ti][tj]);
    }
  }

  const int rq = (lane >> 4) * 4;
#pragma unroll
  for (int ti = 0; ti < 4; ++ti)
#pragma unroll
    for (int tj = 0; tj < 4; ++tj) {
      const int col = tj * 16 + lm;
      const float bv = bd2[col];
#pragma unroll
      for (int r = 0; r < 4; ++r) {
        const size_t row = row0 + wr + ti * 16 + rq + r;
        out[row * 64 + col] = acc[ti][tj][r] + bv;
      }
    }
}

// ---------------------------------------------------------------------------
// Host driver
// ---------------------------------------------------------------------------
extern "C" void kernel_launch(void* const* d_in, const int* in_sizes, int n_in,
                              void* d_out, int out_size, void* d_ws, size_t ws_size,
                              hipStream_t stream)
{
  (void)in_sizes; (void)n_in; (void)out_size; (void)ws_size;
  const float* inputs = (const float*)d_in[0];
  const float* mask   = (const float*)d_in[1];
  const float* adj    = (const float*)d_in[2];
  const float* Wp1    = (const float*)d_in[3];
  const float* bp1    = (const float*)d_in[4];
  const float* Wp2    = (const float*)d_in[5];
  const float* bp2    = (const float*)d_in[6];
  const float* Wz_f   = (const float*)d_in[7];
  const float* Wr_f   = (const float*)d_in[8];
  const float* Wc_f   = (const float*)d_in[9];
  const float* bz_f   = (const float*)d_in[10];
  const float* br_f   = (const float*)d_in[11];
  const float* bc_f   = (const float*)d_in[12];
  const float* Wz_r   = (const float*)d_in[13];
  const float* Wr_r   = (const float*)d_in[14];
  const float* Wc_r   = (const float*)d_in[15];
  const float* bz_r   = (const float*)d_in[16];
  const float* br_r   = (const float*)d_in[17];
  const float* bc_r   = (const float*)d_in[18];
  const float* Wd1    = (const float*)d_in[19];
  const float* bd1    = (const float*)d_in[20];
  const float* Wd2    = (const float*)d_in[21];
  const float* bd2    = (const float*)d_in[22];

  float* ws = (float*)d_ws;
  float* S0 = ws;                                   // TOT
  float* X  = S0 + TOT;                             // TOT*64
  float* H  = X + (size_t)TOT * 64;                 // 4*HSZ [dir*2+l]
  float* Z  = H + 4 * HSZ;                          // 2*HSZ
  float* RH = Z + 2 * HSZ;                          // 2*HSZ
  ushort_t* ADJH = (ushort_t*)(RH + 2 * HSZ);       // 1M ushorts
  ushort_t* ADJL = ADJH + (size_t)1024 * 1024;
  ushort_t* WH   = ADJL + (size_t)1024 * 1024;      // WTOT
  ushort_t* WL   = WH + WTOT;
  float* U = (float*)(WL + WTOT);                   // union region
  ushort_t* G1TH = (ushort_t*)U;                    // 4M ushorts
  ushort_t* G1TL = G1TH + (size_t)2 * 16 * 128 * 1024;
  ushort_t* G2TH = G1TL + (size_t)2 * 16 * 128 * 1024;
  ushort_t* G2TL = G2TH + (size_t)16 * 128 * 1024;  // ends at 12.58M ushorts
  float* D1 = U;                                    // 32768*256 floats (aliases G after loop)

  hipMemsetAsync(H, 0, 4 * HSZ * sizeof(float), stream);

  seq_kernel<<<dim3((HALF + 255) / 256), 256, 0, stream>>>(inputs, S0);
  wprep_kernel<<<dim3((WTOT + 255) / 256), 256, 0, stream>>>(
      Wz_f, Wr_f, Wc_f, Wz_r, Wr_r, Wc_r, Wp2, Wd1, Wd2, WH, WL);
  adjsplit_kernel<<<dim3(4096), 256, 0, stream>>>(adj, ADJH, ADJL);
  proj_mfma<<<dim3(TOT / 256), 256, 0, stream>>>(S0, mask, Wp1, bp1, bp2, WH, WL, X);

  for (int t = 0; t < Tn; ++t) {
    for (int l = 0; l < Ln; ++l) {
      const float* x0 = (l == 0) ? (X + (size_t)t * HSZ) : H;
      const float* x1 = (l == 0) ? (X + (size_t)(Tn - 1 - t) * HSZ) : (H + 2 * HSZ);
      float* h0 = H + (size_t)l * HSZ;
      float* h1 = H + (size_t)(2 + l) * HSZ;

      prez_mfma<<<dim3(128, 1, 2), 256, 0, stream>>>(
          x0, x1, h0, h1, WH, WL, l, G1TH, G1TL);
      conv_mfma<0><<<dim3(8, 16, 2), 256, 0, stream>>>(
          ADJH, ADJL, G1TH, G1TL,
          bz_f + l * 64, bz_r + l * 64, br_f + l * 64, br_r + l * 64,
          Z, RH, h0, h1);
      prec_mfma<<<dim3(128, 1, 2), 128, 0, stream>>>(
          x0, x1, RH, WH, WL, l, G2TH, G2TL);
      conv_mfma<1><<<dim3(8, 16, 1), 256, 0, stream>>>(
          ADJH, ADJL, G2TH, G2TL,
          bc_f + l * 64, bc_r + l * 64, bc_f + l * 64, bc_r + l * 64,
          Z, RH, h0, h1);
    }
  }

  dec1_mfma<<<dim3(256, 2), 256, 0, stream>>>(H, WH, WL, bd1, D1);
  dec2_mfma<<<dim3(128), 256, 0, stream>>>(D1, WH, WL, bd2, (float*)d_out);
}